// Round 2
// baseline (1847.732 us; speedup 1.0000x reference)
//
#include <hip/hip_runtime.h>
#include <math.h>

#define HIDF 256
#define FPDIM 1034

__device__ __forceinline__ float relu_f(float v) { return fmaxf(v, 0.f); }

// ---------------- GEMM: C = act(A @ W + bias) ----------------
// A: MxK row-major, W: KxN row-major, C: MxN row-major.
// BM=BN=128, BK=16, 256 threads, 8x8 outputs per thread.
// ACT: 0=none, 1=relu, 2=tanh
template <int ACT>
__global__ __launch_bounds__(256) void gemm_f32(
    const float* __restrict__ A, const float* __restrict__ W,
    const float* __restrict__ bias, float* __restrict__ C,
    int M, int N, int K)
{
    __shared__ float As[16][128];
    __shared__ float Bs[16][128];
    const int m0 = blockIdx.y * 128;
    const int n0 = blockIdx.x * 128;
    const int tid = threadIdx.x;
    const int tx = tid & 15;
    const int ty = tid >> 4;

    float acc[8][8];
#pragma unroll
    for (int i = 0; i < 8; ++i)
#pragma unroll
        for (int j = 0; j < 8; ++j) acc[i][j] = 0.f;

    for (int k0 = 0; k0 < K; k0 += 16) {
        // A tile 128x16 -> As[k][m] (transposed store)
#pragma unroll
        for (int i = 0; i < 2; ++i) {
            int idx = tid + i * 256;      // float4 index 0..511
            int r = idx >> 2;             // 0..127
            int c4 = (idx & 3) << 2;      // 0,4,8,12
            int row = m0 + r;
            float4 v = make_float4(0.f, 0.f, 0.f, 0.f);
            if (row < M) v = *(const float4*)(A + (size_t)row * K + k0 + c4);
            As[c4 + 0][r] = v.x;
            As[c4 + 1][r] = v.y;
            As[c4 + 2][r] = v.z;
            As[c4 + 3][r] = v.w;
        }
        // B tile 16x128 -> Bs[k][n]
#pragma unroll
        for (int i = 0; i < 2; ++i) {
            int idx = tid + i * 256;
            int kr = idx >> 5;            // 0..15
            int c4 = (idx & 31) << 2;     // 0..124
            float4 v = *(const float4*)(W + (size_t)(k0 + kr) * N + n0 + c4);
            *(float4*)&Bs[kr][c4] = v;
        }
        __syncthreads();
#pragma unroll
        for (int k = 0; k < 16; ++k) {
            float a[8], b[8];
            *(float4*)&a[0] = *(const float4*)&As[k][ty << 3];
            *(float4*)&a[4] = *(const float4*)&As[k][(ty << 3) + 4];
            *(float4*)&b[0] = *(const float4*)&Bs[k][tx << 3];
            *(float4*)&b[4] = *(const float4*)&Bs[k][(tx << 3) + 4];
#pragma unroll
            for (int i = 0; i < 8; ++i)
#pragma unroll
                for (int j = 0; j < 8; ++j)
                    acc[i][j] = fmaf(a[i], b[j], acc[i][j]);
        }
        __syncthreads();
    }

#pragma unroll
    for (int i = 0; i < 8; ++i) {
        int row = m0 + (ty << 3) + i;
        if (row < M) {
#pragma unroll
            for (int jj = 0; jj < 2; ++jj) {
                int col = n0 + (tx << 3) + jj * 4;
                float4 o;
                o.x = acc[i][jj * 4 + 0];
                o.y = acc[i][jj * 4 + 1];
                o.z = acc[i][jj * 4 + 2];
                o.w = acc[i][jj * 4 + 3];
                if (bias != nullptr) {
                    float4 bv = *(const float4*)(bias + col);
                    o.x += bv.x; o.y += bv.y; o.z += bv.z; o.w += bv.w;
                }
                if (ACT == 1) {
                    o.x = relu_f(o.x); o.y = relu_f(o.y);
                    o.z = relu_f(o.z); o.w = relu_f(o.w);
                } else if (ACT == 2) {
                    o.x = tanhf(o.x); o.y = tanhf(o.y);
                    o.z = tanhf(o.z); o.w = tanhf(o.w);
                }
                *(float4*)(C + (size_t)row * N + col) = o;
            }
        }
    }
}

// ---------------- counting sort of edges by dst ----------------
__global__ void count_k(const int* __restrict__ dst, int* __restrict__ cnt, int E)
{
    int e = blockIdx.x * blockDim.x + threadIdx.x;
    if (e < E) atomicAdd(&cnt[dst[e]], 1);
}

__global__ __launch_bounds__(1024) void scan_k(
    const int* __restrict__ cnt, int* __restrict__ offs,
    int* __restrict__ cursor, int n)
{
    __shared__ int sh[1024];
    __shared__ int carry_s;
    int tid = threadIdx.x;
    if (tid == 0) carry_s = 0;
    __syncthreads();
    for (int base = 0; base < n; base += 1024) {
        int v = (base + tid < n) ? cnt[base + tid] : 0;
        sh[tid] = v;
        __syncthreads();
        for (int off = 1; off < 1024; off <<= 1) {
            int t = (tid >= off) ? sh[tid - off] : 0;
            __syncthreads();
            sh[tid] += t;
            __syncthreads();
        }
        int carry = carry_s;
        int excl = carry + sh[tid] - v;
        if (base + tid < n) { offs[base + tid] = excl; cursor[base + tid] = excl; }
        __syncthreads();
        if (tid == 1023) carry_s = carry + sh[1023];
        __syncthreads();
    }
    if (tid == 0) offs[n] = carry_s;
}

__global__ void scatter_k(const int* __restrict__ dst, int* __restrict__ cursor,
                          int* __restrict__ perm, int E)
{
    int e = blockIdx.x * blockDim.x + threadIdx.x;
    if (e < E) {
        int p = atomicAdd(&cursor[dst[e]], 1);
        perm[p] = e;
    }
}

// start[g] = lower_bound(batch, g), g in [0,B]; batch sorted
__global__ void start_k(const int* __restrict__ batch, int* __restrict__ start,
                        int n, int B)
{
    int g = blockIdx.x * blockDim.x + threadIdx.x;
    if (g > B) return;
    int lo = 0, hi = n;
    while (lo < hi) {
        int mid = (lo + hi) >> 1;
        if (batch[mid] < g) lo = mid + 1; else hi = mid;
    }
    start[g] = lo;
}

// ---------------- edge aggregation (one wave per dst node) ----------------
// aggr[d] = relu(xw[d] + lb) + sum_{e in in(d)} relu(xw[src_e] + ea_e*we + lb)
__global__ __launch_bounds__(256) void aggregate_k(
    const float* __restrict__ xw, const float* __restrict__ we,
    const float* __restrict__ lb, const int* __restrict__ src,
    const float* __restrict__ ea, const int* __restrict__ perm,
    const int* __restrict__ offs, float* __restrict__ out, int n)
{
    int w = (blockIdx.x * blockDim.x + threadIdx.x) >> 6;
    if (w >= n) return;
    int lane = threadIdx.x & 63;
    int f = lane << 2;
    float4 we4 = *(const float4*)(we + f);
    float4 lb4 = *(const float4*)(lb + f);
    float4 xs = *(const float4*)(xw + (size_t)w * HIDF + f);
    float4 acc;
    acc.x = relu_f(xs.x + lb4.x);
    acc.y = relu_f(xs.y + lb4.y);
    acc.z = relu_f(xs.z + lb4.z);
    acc.w = relu_f(xs.w + lb4.w);
    int e0 = offs[w], e1 = offs[w + 1];
    for (int ii = e0; ii < e1; ++ii) {
        int e = perm[ii];
        int s = src[e];
        float a = ea[e];
        float4 v = *(const float4*)(xw + (size_t)s * HIDF + f);
        acc.x += relu_f(fmaf(a, we4.x, v.x) + lb4.x);
        acc.y += relu_f(fmaf(a, we4.y, v.y) + lb4.y);
        acc.z += relu_f(fmaf(a, we4.z, v.z) + lb4.z);
        acc.w += relu_f(fmaf(a, we4.w, v.w) + lb4.w);
    }
    *(float4*)(out + (size_t)w * HIDF + f) = acc;
}

// ---------------- gate: gate[i] = sigmoid(dot(t[i], g2w) + g2b) ----------------
__global__ __launch_bounds__(256) void gate_k(
    const float* __restrict__ t, const float* __restrict__ g2w,
    const float* __restrict__ g2b, float* __restrict__ gate, int n)
{
    int w = (blockIdx.x * blockDim.x + threadIdx.x) >> 6;
    if (w >= n) return;
    int lane = threadIdx.x & 63;
    float4 tv = *(const float4*)(t + (size_t)w * HIDF + (lane << 2));
    float4 g = *(const float4*)(g2w + (lane << 2));
    float s = tv.x * g.x + tv.y * g.y + tv.z * g.z + tv.w * g.w;
    for (int o = 32; o; o >>= 1) s += __shfl_xor(s, o);
    if (lane == 0) gate[w] = 1.f / (1.f + expf(-(s + g2b[0])));
}

// ---------------- pooling: pooled[g] = sum_{i in graph g} x[i]*gate[i] ----------------
__global__ __launch_bounds__(256) void pool_k(
    const float* __restrict__ x, const float* __restrict__ gate,
    const int* __restrict__ start, float* __restrict__ pooled, int B)
{
    int w = (blockIdx.x * blockDim.x + threadIdx.x) >> 6;
    if (w >= B) return;
    int lane = threadIdx.x & 63;
    int f = lane << 2;
    float4 acc = make_float4(0.f, 0.f, 0.f, 0.f);
    int i0 = start[w], i1 = start[w + 1];
    for (int i = i0; i < i1; ++i) {
        float gi = gate[i];
        float4 v = *(const float4*)(x + (size_t)i * HIDF + f);
        acc.x = fmaf(gi, v.x, acc.x);
        acc.y = fmaf(gi, v.y, acc.y);
        acc.z = fmaf(gi, v.z, acc.z);
        acc.w = fmaf(gi, v.w, acc.w);
    }
    *(float4*)(pooled + (size_t)w * HIDF + f) = acc;
}

// ---------------- fc1: h = [pooled, fp] @ fc1_w + fc1_b ----------------
#define FC1_G 8
#define FC1_K (HIDF + FPDIM)   // 1290
__global__ __launch_bounds__(256) void fc1_k(
    const float* __restrict__ pooled, const float* __restrict__ fp,
    const float* __restrict__ w, const float* __restrict__ b,
    float* __restrict__ h, int B)
{
    __shared__ float in[FC1_G][1292];  // row stride 1292 floats = 5168 B (16B aligned)
    int g0 = blockIdx.x * FC1_G;
    int tid = threadIdx.x;
    for (int r = 0; r < FC1_G; ++r) {
        int g = g0 + r;
        in[r][tid] = (g < B) ? pooled[(size_t)g * HIDF + tid] : 0.f;
        for (int c = tid; c < FPDIM; c += 256)
            in[r][HIDF + c] = (g < B) ? fp[(size_t)g * FPDIM + c] : 0.f;
    }
    __syncthreads();
    int j = tid;
    float acc[FC1_G];
#pragma unroll
    for (int r = 0; r < FC1_G; ++r) acc[r] = b[j];
    int k = 0;
    for (; k + 4 <= FC1_K; k += 4) {
        float w0 = w[(size_t)(k + 0) * HIDF + j];
        float w1 = w[(size_t)(k + 1) * HIDF + j];
        float w2 = w[(size_t)(k + 2) * HIDF + j];
        float w3 = w[(size_t)(k + 3) * HIDF + j];
#pragma unroll
        for (int r = 0; r < FC1_G; ++r) {
            float4 iv = *(const float4*)&in[r][k];
            acc[r] = fmaf(iv.x, w0, acc[r]);
            acc[r] = fmaf(iv.y, w1, acc[r]);
            acc[r] = fmaf(iv.z, w2, acc[r]);
            acc[r] = fmaf(iv.w, w3, acc[r]);
        }
    }
    for (; k < FC1_K; ++k) {
        float wk = w[(size_t)k * HIDF + j];
#pragma unroll
        for (int r = 0; r < FC1_G; ++r) acc[r] = fmaf(in[r][k], wk, acc[r]);
    }
    for (int r = 0; r < FC1_G; ++r) {
        int g = g0 + r;
        if (g < B) h[(size_t)g * HIDF + j] = acc[r];
    }
}

// ---------------- BN stats per column ----------------
__global__ __launch_bounds__(256) void bnstats_k(
    const float* __restrict__ h, float* __restrict__ mu,
    float* __restrict__ rs, int B)
{
    int j = blockIdx.x;
    int tid = threadIdx.x;
    float s = 0.f, s2 = 0.f;
    for (int g = tid; g < B; g += 256) {
        float v = h[(size_t)g * HIDF + j];
        s += v;
        s2 = fmaf(v, v, s2);
    }
    __shared__ float sh[256], sh2[256];
    sh[tid] = s; sh2[tid] = s2;
    __syncthreads();
    for (int o = 128; o; o >>= 1) {
        if (tid < o) { sh[tid] += sh[tid + o]; sh2[tid] += sh2[tid + o]; }
        __syncthreads();
    }
    if (tid == 0) {
        float m = sh[0] / (float)B;
        float var = sh2[0] / (float)B - m * m;
        if (var < 0.f) var = 0.f;
        mu[j] = m;
        rs[j] = rsqrtf(var + 1e-5f);
    }
}

// ---------------- final: out[g] = dot(relu(BN(h[g])), fc2w) + fc2b ----------------
__global__ __launch_bounds__(256) void final_k(
    const float* __restrict__ h, const float* __restrict__ mu,
    const float* __restrict__ rs, const float* __restrict__ gamma,
    const float* __restrict__ beta, const float* __restrict__ w2,
    const float* __restrict__ b2, float* __restrict__ out, int B)
{
    int g = blockIdx.x;
    int j = threadIdx.x;
    float v = h[(size_t)g * HIDF + j];
    v = (v - mu[j]) * rs[j] * gamma[j] + beta[j];
    v = relu_f(v);
    float term = v * w2[j];
    __shared__ float sh[256];
    sh[j] = term;
    __syncthreads();
    for (int o = 128; o; o >>= 1) {
        if (j < o) sh[j] += sh[j + o];
        __syncthreads();
    }
    if (j == 0) out[g] = sh[0] + b2[0];
}

extern "C" void kernel_launch(void* const* d_in, const int* in_sizes, int n_in,
                              void* d_out, int out_size, void* d_ws, size_t ws_size,
                              hipStream_t stream)
{
    const float* x      = (const float*)d_in[0];
    const int*   ei     = (const int*)d_in[1];
    const float* ea     = (const float*)d_in[2];
    const float* fp     = (const float*)d_in[3];
    const int*   batch  = (const int*)d_in[4];
    const float* lin_w  = (const float*)d_in[5];
    const float* lin_b  = (const float*)d_in[6];
    const float* upd_w  = (const float*)d_in[7];
    const float* upd_b  = (const float*)d_in[8];
    const float* g1w    = (const float*)d_in[9];
    const float* g1b    = (const float*)d_in[10];
    const float* g2w    = (const float*)d_in[11];
    const float* g2b    = (const float*)d_in[12];
    const float* fc1w   = (const float*)d_in[13];
    const float* fc1b   = (const float*)d_in[14];
    const float* gamma  = (const float*)d_in[15];
    const float* beta   = (const float*)d_in[16];
    const float* fc2w   = (const float*)d_in[17];
    const float* fc2b   = (const float*)d_in[18];
    float* out = (float*)d_out;

    const int n = in_sizes[0] / HIDF;       // 50000
    const int E = in_sizes[1] / 2;          // 800000
    const int B = in_sizes[3] / FPDIM;      // 2000
    const int L = in_sizes[5] / (257 * 256);// 4
    const int* srcArr = ei;
    const int* dstArr = ei + E;

    // ---- workspace layout (16B aligned chunks) ----
    char* w = (char*)d_ws;
    float* buf0 = (float*)w;            w += (size_t)n * HIDF * 4;
    float* buf1 = (float*)w;            w += (size_t)n * HIDF * 4;
    int* perm   = (int*)w;              w += (size_t)E * 4;
    int* offs   = (int*)w;              w += ((size_t)n + 4) * 4;
    int* cursor = (int*)w;              w += ((size_t)n + 4) * 4;
    int* cnt    = (int*)w;              w += (size_t)n * 4;
    int* startA = (int*)w;              w += ((size_t)B + 4) * 4;
    float* gateA= (float*)w;            w += (size_t)n * 4;
    float* pooled=(float*)w;            w += (size_t)B * HIDF * 4;
    float* h    = (float*)w;            w += (size_t)B * HIDF * 4;
    float* mu   = (float*)w;            w += 256 * 4;
    float* rs   = (float*)w;            w += 256 * 4;

    // ---- build CSR permutation of edges by dst (once per launch) ----
    hipMemsetAsync(cnt, 0, (size_t)n * 4, stream);
    count_k<<<(E + 255) / 256, 256, 0, stream>>>(dstArr, cnt, E);
    scan_k<<<1, 1024, 0, stream>>>(cnt, offs, cursor, n);
    scatter_k<<<(E + 255) / 256, 256, 0, stream>>>(dstArr, cursor, perm, E);
    start_k<<<(B + 256) / 256, 256, 0, stream>>>(batch, startA, n, B);

    // ---- message passing layers ----
    dim3 gg(HIDF / 128, (n + 127) / 128);
    const float* xin = x;
    float* pa = buf0;
    float* pb = buf1;
    for (int l = 0; l < L; ++l) {
        const float* wn = lin_w + (size_t)l * 257 * 256;  // 256x256
        const float* we = wn + 256 * 256;                 // row 256 (1x256)
        const float* lb = lin_b + (size_t)l * 256;
        float* xw = pa;
        gemm_f32<0><<<gg, 256, 0, stream>>>(xin, wn, nullptr, xw, n, HIDF, HIDF);
        aggregate_k<<<(n * 64 + 255) / 256, 256, 0, stream>>>(
            xw, we, lb, srcArr, ea, perm, offs, pb, n);
        gemm_f32<1><<<gg, 256, 0, stream>>>(pb, upd_w + (size_t)l * 256 * 256,
                                            upd_b + (size_t)l * 256, pa, n, HIDF, HIDF);
        xin = pa;
        float* t = pa; pa = pb; pb = t;
    }

    // ---- gating + pooling ----
    // Scratch = whichever ping-pong buffer xin does NOT live in (parity-proof).
    float* t = (xin == buf1) ? buf0 : buf1;
    gemm_f32<2><<<gg, 256, 0, stream>>>(xin, g1w, g1b, t, n, HIDF, HIDF);
    gate_k<<<(n * 64 + 255) / 256, 256, 0, stream>>>(t, g2w, g2b, gateA, n);
    pool_k<<<(B * 64 + 255) / 256, 256, 0, stream>>>(xin, gateA, startA, pooled, B);

    // ---- head ----
    fc1_k<<<(B + FC1_G - 1) / FC1_G, 256, 0, stream>>>(pooled, fp, fc1w, fc1b, h, B);
    bnstats_k<<<256, 256, 0, stream>>>(h, mu, rs, B);
    final_k<<<B, 256, 0, stream>>>(h, mu, rs, gamma, beta, fc2w, fc2b, out, B);
}

// Round 4
// 1170.793 us; speedup vs baseline: 1.5782x; 1.5782x over previous
//
#include <hip/hip_runtime.h>
#include <math.h>

#define HIDF 256
#define FPDIM 1034
#define MPAD 50048   // 50000 rounded up to 128

typedef _Float16 f16x8 __attribute__((ext_vector_type(8)));
typedef _Float16 f16x4 __attribute__((ext_vector_type(4)));
typedef float f32x4 __attribute__((ext_vector_type(4)));

__device__ __forceinline__ float relu_f(float v) { return fmaxf(v, 0.f); }

// ---------------- pad/copy x fp32 -> xf [MPAD][256], zero tail ----------------
__global__ __launch_bounds__(256) void padx_k(
    const float* __restrict__ x, float* __restrict__ xf, int n)
{
    int i = blockIdx.x * 256 + threadIdx.x;   // float4-group index
    int row = i >> 6;
    if (row >= MPAD) return;
    float4 v = make_float4(0.f, 0.f, 0.f, 0.f);
    if (row < n) v = ((const float4*)x)[i];
    ((float4*)xf)[i] = v;
}

// ------- weight: W fp32 [K=256][N=256] -> Wt^T split fp16 hi/lo [N][K] --------
__global__ __launch_bounds__(256) void convw_k(
    const float* __restrict__ w, _Float16* __restrict__ whi,
    _Float16* __restrict__ wlo)
{
    int i = blockIdx.x * 256 + threadIdx.x;   // 0..65535
    int nn = i >> 8, kk = i & 255;
    float v = w[kk * 256 + nn];
    _Float16 h = (_Float16)v;
    _Float16 l = (_Float16)(v - (float)h);
    whi[i] = h;
    wlo[i] = l;
}

// ---------------- split-fp16 MFMA GEMM: C = act(A @ Wt^T + bias) --------------
// A: [M][K] fp32 row-major (M mult of 128). Whi/Wlo: [N][K] fp16 row-major.
// BM=BN=128, BK=64, 4 waves (2x2 of 64x64), mfma_f32_16x16x32_f16.
// acc = Ahi*Whi + Ahi*Wlo + Alo*Whi  (~22-bit effective mantissa)
// ACT: 0 none, 1 relu, 2 tanh. Output fp32.
template <int ACT>
__global__ __launch_bounds__(256) void gemm_split(
    const float* __restrict__ A, const _Float16* __restrict__ Whi,
    const _Float16* __restrict__ Wlo, const float* __restrict__ bias,
    float* __restrict__ C, int M, int N, int K)
{
    __shared__ _Float16 Ah[128 * 64];
    __shared__ _Float16 Al[128 * 64];
    __shared__ _Float16 Bh[128 * 64];
    __shared__ _Float16 Bl[128 * 64];
    const int tid = threadIdx.x;
    const int wave = tid >> 6, lane = tid & 63;
    const int m0 = blockIdx.y * 128, n0 = blockIdx.x * 128;
    const int wr = wave >> 1, wc = wave & 1;

    f32x4 acc[4][4];
#pragma unroll
    for (int i = 0; i < 4; ++i)
#pragma unroll
        for (int j = 0; j < 4; ++j) acc[i][j] = (f32x4){0.f, 0.f, 0.f, 0.f};

    const int lrow = lane >> 3;           // 0..7
    const int lcol8 = (lane & 7) * 8;     // fp16 units within row

    for (int k0 = 0; k0 < K; k0 += 64) {
        // ---- B tiles: pre-split fp16, async global->LDS (16B/lane) ----
#pragma unroll
        for (int i = 0; i < 4; ++i) {
            int iss = wave * 4 + i;       // 0..15, each covers 8 rows
            int row = 8 * iss + lrow;
            const _Float16* gh = Whi + (size_t)(n0 + row) * K + k0 + lcol8;
            const _Float16* gl = Wlo + (size_t)(n0 + row) * K + k0 + lcol8;
            __builtin_amdgcn_global_load_lds(
                (const __attribute__((address_space(1))) void*)gh,
                (__attribute__((address_space(3))) void*)(Bh + iss * 512), 16, 0, 0);
            __builtin_amdgcn_global_load_lds(
                (const __attribute__((address_space(1))) void*)gl,
                (__attribute__((address_space(3))) void*)(Bl + iss * 512), 16, 0, 0);
        }
        // ---- A tile: fp32 load, split to hi/lo fp16, ds_write ----
#pragma unroll
        for (int i = 0; i < 8; ++i) {
            int f = i * 256 + tid;        // float4 index: 128 rows x 16 fl4/row
            int row = f >> 4;
            int c4 = (f & 15) * 4;
            float4 v = *(const float4*)(A + (size_t)(m0 + row) * K + k0 + c4);
            f16x4 h4, l4;
            h4[0] = (_Float16)v.x; l4[0] = (_Float16)(v.x - (float)h4[0]);
            h4[1] = (_Float16)v.y; l4[1] = (_Float16)(v.y - (float)h4[1]);
            h4[2] = (_Float16)v.z; l4[2] = (_Float16)(v.z - (float)h4[2]);
            h4[3] = (_Float16)v.w; l4[3] = (_Float16)(v.w - (float)h4[3]);
            *(f16x4*)&Ah[row * 64 + c4] = h4;
            *(f16x4*)&Al[row * 64 + c4] = l4;
        }
        __syncthreads();
#pragma unroll
        for (int kk = 0; kk < 2; ++kk) {
            const int kb = kk * 32 + (lane >> 4) * 8;
            f16x8 ah[4], al[4], bh[4], bl[4];
#pragma unroll
            for (int mi = 0; mi < 4; ++mi) {
                int r = (wr * 64 + mi * 16 + (lane & 15)) * 64 + kb;
                ah[mi] = *(const f16x8*)&Ah[r];
                al[mi] = *(const f16x8*)&Al[r];
            }
#pragma unroll
            for (int ni = 0; ni < 4; ++ni) {
                int r = (wc * 64 + ni * 16 + (lane & 15)) * 64 + kb;
                bh[ni] = *(const f16x8*)&Bh[r];
                bl[ni] = *(const f16x8*)&Bl[r];
            }
#pragma unroll
            for (int mi = 0; mi < 4; ++mi)
#pragma unroll
                for (int ni = 0; ni < 4; ++ni) {
                    acc[mi][ni] = __builtin_amdgcn_mfma_f32_16x16x32_f16(
                        ah[mi], bh[ni], acc[mi][ni], 0, 0, 0);
                    acc[mi][ni] = __builtin_amdgcn_mfma_f32_16x16x32_f16(
                        ah[mi], bl[ni], acc[mi][ni], 0, 0, 0);
                    acc[mi][ni] = __builtin_amdgcn_mfma_f32_16x16x32_f16(
                        al[mi], bh[ni], acc[mi][ni], 0, 0, 0);
                }
        }
        __syncthreads();
    }

    // epilogue: C col = lane&15, row = (lane>>4)*4 + r  [m89-verified]
    const int crow0 = m0 + wr * 64 + (lane >> 4) * 4;
    const int ccol0 = n0 + wc * 64 + (lane & 15);
#pragma unroll
    for (int mi = 0; mi < 4; ++mi) {
#pragma unroll
        for (int ni = 0; ni < 4; ++ni) {
            int col = ccol0 + ni * 16;
            float bv = bias ? bias[col] : 0.f;
#pragma unroll
            for (int r = 0; r < 4; ++r) {
                int row = crow0 + mi * 16 + r;
                float v = acc[mi][ni][r] + bv;
                if (ACT == 1) v = relu_f(v);
                else if (ACT == 2) v = tanhf(v);
                C[(size_t)row * N + col] = v;
            }
        }
    }
}

// ---------------- counting sort of edges by dst ----------------
__global__ void count_k(const int* __restrict__ dst, int* __restrict__ cnt, int E)
{
    int e = blockIdx.x * blockDim.x + threadIdx.x;
    if (e < E) atomicAdd(&cnt[dst[e]], 1);
}

__global__ __launch_bounds__(1024) void scan_k(
    const int* __restrict__ cnt, int* __restrict__ offs,
    int* __restrict__ cursor, int n)
{
    __shared__ int sh[1024];
    __shared__ int carry_s;
    int tid = threadIdx.x;
    if (tid == 0) carry_s = 0;
    __syncthreads();
    for (int base = 0; base < n; base += 1024) {
        int v = (base + tid < n) ? cnt[base + tid] : 0;
        sh[tid] = v;
        __syncthreads();
        for (int off = 1; off < 1024; off <<= 1) {
            int t = (tid >= off) ? sh[tid - off] : 0;
            __syncthreads();
            sh[tid] += t;
            __syncthreads();
        }
        int carry = carry_s;
        int excl = carry + sh[tid] - v;
        if (base + tid < n) { offs[base + tid] = excl; cursor[base + tid] = excl; }
        __syncthreads();
        if (tid == 1023) carry_s = carry + sh[1023];
        __syncthreads();
    }
    if (tid == 0) offs[n] = carry_s;
}

// scatter: materialize src/ea in dst-sorted order (kills one indirection)
__global__ void scatter_k(const int* __restrict__ dst, const int* __restrict__ src,
                          const float* __restrict__ ea, int* __restrict__ cursor,
                          int* __restrict__ srcS, float* __restrict__ eaS, int E)
{
    int e = blockIdx.x * blockDim.x + threadIdx.x;
    if (e < E) {
        int p = atomicAdd(&cursor[dst[e]], 1);
        srcS[p] = src[e];
        eaS[p] = ea[e];
    }
}

// start[g] = lower_bound(batch, g), g in [0,B]; batch sorted
__global__ void start_k(const int* __restrict__ batch, int* __restrict__ start,
                        int n, int B)
{
    int g = blockIdx.x * blockDim.x + threadIdx.x;
    if (g > B) return;
    int lo = 0, hi = n;
    while (lo < hi) {
        int mid = (lo + hi) >> 1;
        if (batch[mid] < g) lo = mid + 1; else hi = mid;
    }
    start[g] = lo;
}

// ---------------- edge aggregation (one wave per dst node), fp32 --------------
// out[d] = relu(xw[d]+lb) + sum_e relu(xw[srcS]+eaS*we+lb)
__global__ __launch_bounds__(256) void aggregate_k(
    const float* __restrict__ xw, const float* __restrict__ we,
    const float* __restrict__ lb, const int* __restrict__ srcS,
    const float* __restrict__ eaS, const int* __restrict__ offs,
    float* __restrict__ out, int n)
{
    int w = (blockIdx.x * blockDim.x + threadIdx.x) >> 6;
    if (w >= n) return;
    int lane = threadIdx.x & 63;
    int f = lane << 2;
    float4 we4 = *(const float4*)(we + f);
    float4 lb4 = *(const float4*)(lb + f);
    float4 xs = *(const float4*)(xw + (size_t)w * HIDF + f);
    float4 acc;
    acc.x = relu_f(xs.x + lb4.x);
    acc.y = relu_f(xs.y + lb4.y);
    acc.z = relu_f(xs.z + lb4.z);
    acc.w = relu_f(xs.w + lb4.w);
    int e0 = offs[w], e1 = offs[w + 1];
    int ii = e0;
    for (; ii + 4 <= e1; ii += 4) {
        int s0 = srcS[ii], s1 = srcS[ii + 1], s2 = srcS[ii + 2], s3 = srcS[ii + 3];
        float a0 = eaS[ii], a1 = eaS[ii + 1], a2 = eaS[ii + 2], a3 = eaS[ii + 3];
        float4 v0 = *(const float4*)(xw + (size_t)s0 * HIDF + f);
        float4 v1 = *(const float4*)(xw + (size_t)s1 * HIDF + f);
        float4 v2 = *(const float4*)(xw + (size_t)s2 * HIDF + f);
        float4 v3 = *(const float4*)(xw + (size_t)s3 * HIDF + f);
        acc.x += relu_f(fmaf(a0, we4.x, v0.x) + lb4.x);
        acc.y += relu_f(fmaf(a0, we4.y, v0.y) + lb4.y);
        acc.z += relu_f(fmaf(a0, we4.z, v0.z) + lb4.z);
        acc.w += relu_f(fmaf(a0, we4.w, v0.w) + lb4.w);
        acc.x += relu_f(fmaf(a1, we4.x, v1.x) + lb4.x);
        acc.y += relu_f(fmaf(a1, we4.y, v1.y) + lb4.y);
        acc.z += relu_f(fmaf(a1, we4.z, v1.z) + lb4.z);
        acc.w += relu_f(fmaf(a1, we4.w, v1.w) + lb4.w);
        acc.x += relu_f(fmaf(a2, we4.x, v2.x) + lb4.x);
        acc.y += relu_f(fmaf(a2, we4.y, v2.y) + lb4.y);
        acc.z += relu_f(fmaf(a2, we4.z, v2.z) + lb4.z);
        acc.w += relu_f(fmaf(a2, we4.w, v2.w) + lb4.w);
        acc.x += relu_f(fmaf(a3, we4.x, v3.x) + lb4.x);
        acc.y += relu_f(fmaf(a3, we4.y, v3.y) + lb4.y);
        acc.z += relu_f(fmaf(a3, we4.z, v3.z) + lb4.z);
        acc.w += relu_f(fmaf(a3, we4.w, v3.w) + lb4.w);
    }
    for (; ii < e1; ++ii) {
        int s0 = srcS[ii];
        float a0 = eaS[ii];
        float4 v0 = *(const float4*)(xw + (size_t)s0 * HIDF + f);
        acc.x += relu_f(fmaf(a0, we4.x, v0.x) + lb4.x);
        acc.y += relu_f(fmaf(a0, we4.y, v0.y) + lb4.y);
        acc.z += relu_f(fmaf(a0, we4.z, v0.z) + lb4.z);
        acc.w += relu_f(fmaf(a0, we4.w, v0.w) + lb4.w);
    }
    *(float4*)(out + (size_t)w * HIDF + f) = acc;
}

// ---------------- gate: gate[i] = sigmoid(dot(t[i], g2w) + g2b) ---------------
__global__ __launch_bounds__(256) void gate_k(
    const float* __restrict__ t, const float* __restrict__ g2w,
    const float* __restrict__ g2b, float* __restrict__ gate, int n)
{
    int w = (blockIdx.x * blockDim.x + threadIdx.x) >> 6;
    if (w >= n) return;
    int lane = threadIdx.x & 63;
    float4 tv = *(const float4*)(t + (size_t)w * HIDF + (lane << 2));
    float4 g = *(const float4*)(g2w + (lane << 2));
    float s = tv.x * g.x + tv.y * g.y + tv.z * g.z + tv.w * g.w;
    for (int o = 32; o; o >>= 1) s += __shfl_xor(s, o);
    if (lane == 0) gate[w] = 1.f / (1.f + expf(-(s + g2b[0])));
}

// ---------------- pooling: pooled[g] = sum_{i in g} x[i]*gate[i] --------------
__global__ __launch_bounds__(256) void pool_k(
    const float* __restrict__ x, const float* __restrict__ gate,
    const int* __restrict__ start, float* __restrict__ pooled, int B)
{
    int w = (blockIdx.x * blockDim.x + threadIdx.x) >> 6;
    if (w >= B) return;
    int lane = threadIdx.x & 63;
    int f = lane << 2;
    float4 acc = make_float4(0.f, 0.f, 0.f, 0.f);
    int i0 = start[w], i1 = start[w + 1];
    for (int i = i0; i < i1; ++i) {
        float gi = gate[i];
        float4 v = *(const float4*)(x + (size_t)i * HIDF + f);
        acc.x = fmaf(gi, v.x, acc.x);
        acc.y = fmaf(gi, v.y, acc.y);
        acc.z = fmaf(gi, v.z, acc.z);
        acc.w = fmaf(gi, v.w, acc.w);
    }
    *(float4*)(pooled + (size_t)w * HIDF + f) = acc;
}

// ---------------- fc1: h = [pooled, fp] @ fc1_w + fc1_b ----------------
#define FC1_G 8
#define FC1_K (HIDF + FPDIM)   // 1290
__global__ __launch_bounds__(256) void fc1_k(
    const float* __restrict__ pooled, const float* __restrict__ fp,
    const float* __restrict__ w, const float* __restrict__ b,
    float* __restrict__ h, int B)
{
    __shared__ float in[FC1_G][1292];  // row stride 5168 B (16B aligned)
    int g0 = blockIdx.x * FC1_G;
    int tid = threadIdx.x;
    for (int r = 0; r < FC1_G; ++r) {
        int g = g0 + r;
        in[r][tid] = (g < B) ? pooled[(size_t)g * HIDF + tid] : 0.f;
        for (int c = tid; c < FPDIM; c += 256)
            in[r][HIDF + c] = (g < B) ? fp[(size_t)g * FPDIM + c] : 0.f;
    }
    __syncthreads();
    int j = tid;
    float acc[FC1_G];
#pragma unroll
    for (int r = 0; r < FC1_G; ++r) acc[r] = b[j];
    int k = 0;
    for (; k + 4 <= FC1_K; k += 4) {
        float w0 = w[(size_t)(k + 0) * HIDF + j];
        float w1 = w[(size_t)(k + 1) * HIDF + j];
        float w2 = w[(size_t)(k + 2) * HIDF + j];
        float w3 = w[(size_t)(k + 3) * HIDF + j];
#pragma unroll
        for (int r = 0; r < FC1_G; ++r) {
            float4 iv = *(const float4*)&in[r][k];
            acc[r] = fmaf(iv.x, w0, acc[r]);
            acc[r] = fmaf(iv.y, w1, acc[r]);
            acc[r] = fmaf(iv.z, w2, acc[r]);
            acc[r] = fmaf(iv.w, w3, acc[r]);
        }
    }
    for (; k < FC1_K; ++k) {
        float wk = w[(size_t)k * HIDF + j];
#pragma unroll
        for (int r = 0; r < FC1_G; ++r) acc[r] = fmaf(in[r][k], wk, acc[r]);
    }
    for (int r = 0; r < FC1_G; ++r) {
        int g = g0 + r;
        if (g < B) h[(size_t)g * HIDF + j] = acc[r];
    }
}

// ---------------- BN stats per column ----------------
__global__ __launch_bounds__(256) void bnstats_k(
    const float* __restrict__ h, float* __restrict__ mu,
    float* __restrict__ rs, int B)
{
    int j = blockIdx.x;
    int tid = threadIdx.x;
    float s = 0.f, s2 = 0.f;
    for (int g = tid; g < B; g += 256) {
        float v = h[(size_t)g * HIDF + j];
        s += v;
        s2 = fmaf(v, v, s2);
    }
    __shared__ float sh[256], sh2[256];
    sh[tid] = s; sh2[tid] = s2;
    __syncthreads();
    for (int o = 128; o; o >>= 1) {
        if (tid < o) { sh[tid] += sh[tid + o]; sh2[tid] += sh2[tid + o]; }
        __syncthreads();
    }
    if (tid == 0) {
        float m = sh[0] / (float)B;
        float var = sh2[0] / (float)B - m * m;
        if (var < 0.f) var = 0.f;
        mu[j] = m;
        rs[j] = rsqrtf(var + 1e-5f);
    }
}

// ---------------- final: out[g] = dot(relu(BN(h[g])), fc2w) + fc2b ------------
__global__ __launch_bounds__(256) void final_k(
    const float* __restrict__ h, const float* __restrict__ mu,
    const float* __restrict__ rs, const float* __restrict__ gamma,
    const float* __restrict__ beta, const float* __restrict__ w2,
    const float* __restrict__ b2, float* __restrict__ out, int B)
{
    int g = blockIdx.x;
    int j = threadIdx.x;
    float v = h[(size_t)g * HIDF + j];
    v = (v - mu[j]) * rs[j] * gamma[j] + beta[j];
    v = relu_f(v);
    float term = v * w2[j];
    __shared__ float sh[256];
    sh[j] = term;
    __syncthreads();
    for (int o = 128; o; o >>= 1) {
        if (j < o) sh[j] += sh[j + o];
        __syncthreads();
    }
    if (j == 0) out[g] = sh[0] + b2[0];
}

extern "C" void kernel_launch(void* const* d_in, const int* in_sizes, int n_in,
                              void* d_out, int out_size, void* d_ws, size_t ws_size,
                              hipStream_t stream)
{
    const float* x      = (const float*)d_in[0];
    const int*   ei     = (const int*)d_in[1];
    const float* ea     = (const float*)d_in[2];
    const float* fp     = (const float*)d_in[3];
    const int*   batch  = (const int*)d_in[4];
    const float* lin_w  = (const float*)d_in[5];
    const float* lin_b  = (const float*)d_in[6];
    const float* upd_w  = (const float*)d_in[7];
    const float* upd_b  = (const float*)d_in[8];
    const float* g1w    = (const float*)d_in[9];
    const float* g1b    = (const float*)d_in[10];
    const float* g2w    = (const float*)d_in[11];
    const float* g2b    = (const float*)d_in[12];
    const float* fc1w   = (const float*)d_in[13];
    const float* fc1b   = (const float*)d_in[14];
    const float* gamma  = (const float*)d_in[15];
    const float* beta   = (const float*)d_in[16];
    const float* fc2w   = (const float*)d_in[17];
    const float* fc2b   = (const float*)d_in[18];
    float* out = (float*)d_out;

    const int n = in_sizes[0] / HIDF;        // 50000
    const int E = in_sizes[1] / 2;           // 800000
    const int B = in_sizes[3] / FPDIM;       // 2000
    const int L = in_sizes[5] / (257 * 256); // 4
    const int* srcArr = ei;
    const int* dstArr = ei + E;

    // ---- workspace layout ----
    char* w = (char*)d_ws;
    float* xf   = (float*)w;  w += (size_t)MPAD * HIDF * 4;   // node state (fp32)
    float* bufA = (float*)w;  w += (size_t)MPAD * HIDF * 4;   // xw / tanh-out
    float* bufB = (float*)w;  w += (size_t)MPAD * HIDF * 4;   // aggr out
    _Float16* whi = (_Float16*)w;  w += (size_t)9 * 65536 * 2;
    _Float16* wlo = (_Float16*)w;  w += (size_t)9 * 65536 * 2;
    int*   srcS   = (int*)w;    w += (size_t)E * 4;
    float* eaS    = (float*)w;  w += (size_t)E * 4;
    int*   offs   = (int*)w;    w += ((size_t)n + 4) * 4;
    int*   cursor = (int*)w;    w += ((size_t)n + 4) * 4;
    int*   cnt    = (int*)w;    w += (size_t)n * 4;
    int*   startA = (int*)w;    w += ((size_t)B + 4) * 4;
    float* gateA  = (float*)w;  w += (size_t)n * 4;
    float* pooled = (float*)w;  w += (size_t)B * HIDF * 4;
    float* h      = (float*)w;  w += (size_t)B * HIDF * 4;
    float* mu     = (float*)w;  w += 256 * 4;
    float* rs     = (float*)w;  w += 256 * 4;

    // ---- CSR build (counting sort by dst) + batch starts ----
    hipMemsetAsync(cnt, 0, (size_t)n * 4, stream);
    count_k<<<(E + 255) / 256, 256, 0, stream>>>(dstArr, cnt, E);
    scan_k<<<1, 1024, 0, stream>>>(cnt, offs, cursor, n);
    scatter_k<<<(E + 255) / 256, 256, 0, stream>>>(dstArr, srcArr, ea, cursor, srcS, eaS, E);
    start_k<<<(B + 256) / 256, 256, 0, stream>>>(batch, startA, n, B);

    // ---- input pad + weight split (hi/lo fp16, transposed) ----
    padx_k<<<(MPAD * 64 + 255) / 256, 256, 0, stream>>>(x, xf, n);
    for (int l = 0; l < L; ++l) {
        convw_k<<<256, 256, 0, stream>>>(lin_w + (size_t)l * 257 * 256,
                                         whi + (size_t)l * 65536, wlo + (size_t)l * 65536);
        convw_k<<<256, 256, 0, stream>>>(upd_w + (size_t)l * 65536,
                                         whi + (size_t)(4 + l) * 65536, wlo + (size_t)(4 + l) * 65536);
    }
    convw_k<<<256, 256, 0, stream>>>(g1w, whi + (size_t)8 * 65536, wlo + (size_t)8 * 65536);

    // ---- message passing: xf -> gemm1 -> bufA -> aggregate -> bufB -> gemm2 -> xf
    dim3 ggm(HIDF / 128, MPAD / 128);
    for (int l = 0; l < L; ++l) {
        const float* we = lin_w + (size_t)l * 257 * 256 + 256 * 256;  // edge row (1x256)
        const float* lb = lin_b + (size_t)l * 256;
        gemm_split<0><<<ggm, 256, 0, stream>>>(xf, whi + (size_t)l * 65536,
                                               wlo + (size_t)l * 65536, nullptr,
                                               bufA, MPAD, HIDF, HIDF);
        aggregate_k<<<(n * 64 + 255) / 256, 256, 0, stream>>>(
            bufA, we, lb, srcS, eaS, offs, bufB, n);
        gemm_split<1><<<ggm, 256, 0, stream>>>(bufB, whi + (size_t)(4 + l) * 65536,
                                               wlo + (size_t)(4 + l) * 65536,
                                               upd_b + (size_t)l * 256, xf, MPAD, HIDF, HIDF);
    }

    // ---- gating + pooling ----
    gemm_split<2><<<ggm, 256, 0, stream>>>(xf, whi + (size_t)8 * 65536,
                                           wlo + (size_t)8 * 65536, g1b,
                                           bufA, MPAD, HIDF, HIDF);
    gate_k<<<(n * 64 + 255) / 256, 256, 0, stream>>>(bufA, g2w, g2b, gateA, n);
    pool_k<<<(B * 64 + 255) / 256, 256, 0, stream>>>(xf, gateA, startA, pooled, B);

    // ---- head (fp32) ----
    fc1_k<<<(B + FC1_G - 1) / FC1_G, 256, 0, stream>>>(pooled, fp, fc1w, fc1b, h, B);
    bnstats_k<<<256, 256, 0, stream>>>(h, mu, rs, B);
    final_k<<<B, 256, 0, stream>>>(h, mu, rs, gamma, beta, fc2w, fc2b, out, B);
}

// Round 5
// 730.899 us; speedup vs baseline: 2.5280x; 1.6019x over previous
//
#include <hip/hip_runtime.h>
#include <math.h>

#define HIDF 256
#define FPDIM 1034
#define MPAD 50048   // 50000 rounded up to 128

typedef _Float16 f16x8 __attribute__((ext_vector_type(8)));
typedef _Float16 f16x4 __attribute__((ext_vector_type(4)));
typedef float f32x4 __attribute__((ext_vector_type(4)));

__device__ __forceinline__ float relu_f(float v) { return fmaxf(v, 0.f); }

// ---------------- x fp32 -> fp16 [MPAD][256], zero pad ----------------
__global__ __launch_bounds__(256) void convxh_k(
    const float* __restrict__ x, _Float16* __restrict__ xh, int n)
{
    int i = blockIdx.x * 256 + threadIdx.x;   // 4-elem group index
    int row = i >> 6;
    if (row >= MPAD) return;
    f16x4 o;
    if (row < n) {
        float4 v = ((const float4*)x)[i];
        o[0] = (_Float16)v.x; o[1] = (_Float16)v.y;
        o[2] = (_Float16)v.z; o[3] = (_Float16)v.w;
    } else {
        o[0] = o[1] = o[2] = o[3] = (_Float16)0.f;
    }
    ((f16x4*)xh)[i] = o;
}

// ------- weight: W fp32 [K=256][N=256] -> W^T split fp16 hi/lo [N][K] --------
__global__ __launch_bounds__(256) void convw_k(
    const float* __restrict__ w, _Float16* __restrict__ whi,
    _Float16* __restrict__ wlo)
{
    int i = blockIdx.x * 256 + threadIdx.x;   // 0..65535
    int nn = i >> 8, kk = i & 255;
    float v = w[kk * 256 + nn];
    _Float16 h = (_Float16)v;
    _Float16 l = (_Float16)(v - (float)h);
    whi[i] = h;
    wlo[i] = l;
}

// ---------------- fp16 MFMA GEMM: C = act(A @ W^T + bias), fp16 out -----------
// A: [M][K] fp16 row-major (M mult of 128). Whi/Wlo: [N][K] fp16 row-major.
// BM=BN=128, BK=64, 4 waves (2x2 of 64x64), mfma_f32_16x16x32_f16.
// acc = A*Whi + A*Wlo (weights at ~22-bit effective precision; A fp16-exact)
// ACT: 0 none, 1 relu, 2 tanh.
template <int ACT>
__global__ __launch_bounds__(256) void gemm_f16(
    const _Float16* __restrict__ A, const _Float16* __restrict__ Whi,
    const _Float16* __restrict__ Wlo, const float* __restrict__ bias,
    _Float16* __restrict__ C, int M, int N, int K)
{
    __shared__ _Float16 As[128 * 64];
    __shared__ _Float16 Bh[128 * 64];
    __shared__ _Float16 Bl[128 * 64];
    const int tid = threadIdx.x;
    const int wave = tid >> 6, lane = tid & 63;
    const int m0 = blockIdx.y * 128, n0 = blockIdx.x * 128;
    const int wr = wave >> 1, wc = wave & 1;

    f32x4 acc[4][4];
#pragma unroll
    for (int i = 0; i < 4; ++i)
#pragma unroll
        for (int j = 0; j < 4; ++j) acc[i][j] = (f32x4){0.f, 0.f, 0.f, 0.f};

    const int lrow = lane >> 3;           // 0..7 (row within 8-row issue group)
    const int lcol8 = (lane & 7) * 8;     // fp16 col offset within 64-col row

    for (int k0 = 0; k0 < K; k0 += 64) {
#pragma unroll
        for (int i = 0; i < 4; ++i) {
            int iss = wave * 4 + i;       // 0..15, each covers 8 rows (1 KiB)
            int row = 8 * iss + lrow;
            const _Float16* ga = A   + (size_t)(m0 + row) * K + k0 + lcol8;
            const _Float16* gh = Whi + (size_t)(n0 + row) * K + k0 + lcol8;
            const _Float16* gl = Wlo + (size_t)(n0 + row) * K + k0 + lcol8;
            __builtin_amdgcn_global_load_lds(
                (const __attribute__((address_space(1))) void*)ga,
                (__attribute__((address_space(3))) void*)(As + iss * 512), 16, 0, 0);
            __builtin_amdgcn_global_load_lds(
                (const __attribute__((address_space(1))) void*)gh,
                (__attribute__((address_space(3))) void*)(Bh + iss * 512), 16, 0, 0);
            __builtin_amdgcn_global_load_lds(
                (const __attribute__((address_space(1))) void*)gl,
                (__attribute__((address_space(3))) void*)(Bl + iss * 512), 16, 0, 0);
        }
        __syncthreads();
#pragma unroll
        for (int kk = 0; kk < 2; ++kk) {
            const int kb = kk * 32 + (lane >> 4) * 8;
            f16x8 af[4], bh[4], bl[4];
#pragma unroll
            for (int mi = 0; mi < 4; ++mi)
                af[mi] = *(const f16x8*)&As[(wr * 64 + mi * 16 + (lane & 15)) * 64 + kb];
#pragma unroll
            for (int ni = 0; ni < 4; ++ni) {
                int r = (wc * 64 + ni * 16 + (lane & 15)) * 64 + kb;
                bh[ni] = *(const f16x8*)&Bh[r];
                bl[ni] = *(const f16x8*)&Bl[r];
            }
#pragma unroll
            for (int mi = 0; mi < 4; ++mi)
#pragma unroll
                for (int ni = 0; ni < 4; ++ni) {
                    acc[mi][ni] = __builtin_amdgcn_mfma_f32_16x16x32_f16(
                        af[mi], bh[ni], acc[mi][ni], 0, 0, 0);
                    acc[mi][ni] = __builtin_amdgcn_mfma_f32_16x16x32_f16(
                        af[mi], bl[ni], acc[mi][ni], 0, 0, 0);
                }
        }
        __syncthreads();
    }

    // epilogue: C col = lane&15, row = (lane>>4)*4 + r  [m89-verified]
    const int crow0 = m0 + wr * 64 + (lane >> 4) * 4;
    const int ccol0 = n0 + wc * 64 + (lane & 15);
#pragma unroll
    for (int mi = 0; mi < 4; ++mi) {
#pragma unroll
        for (int ni = 0; ni < 4; ++ni) {
            int col = ccol0 + ni * 16;
            float bv = bias ? bias[col] : 0.f;
#pragma unroll
            for (int r = 0; r < 4; ++r) {
                int row = crow0 + mi * 16 + r;
                float v = acc[mi][ni][r] + bv;
                if (ACT == 1) v = relu_f(v);
                else if (ACT == 2) v = tanhf(v);
                C[(size_t)row * N + col] = (_Float16)v;
            }
        }
    }
}

// ---------------- counting sort of edges by dst ----------------
__global__ void count_k(const int* __restrict__ dst, int* __restrict__ cnt, int E)
{
    int e = blockIdx.x * blockDim.x + threadIdx.x;
    if (e < E) atomicAdd(&cnt[dst[e]], 1);
}

// 3-phase exclusive scan of cnt[n] (n <= 65536)
__global__ __launch_bounds__(256) void scan1_k(
    const int* __restrict__ cnt, int* __restrict__ offs,
    int* __restrict__ bsum, int n)
{
    __shared__ int sh[256];
    int t = threadIdx.x, idx = blockIdx.x * 256 + t;
    int v = (idx < n) ? cnt[idx] : 0;
    sh[t] = v;
    __syncthreads();
    for (int o = 1; o < 256; o <<= 1) {
        int a = (t >= o) ? sh[t - o] : 0;
        __syncthreads();
        sh[t] += a;
        __syncthreads();
    }
    if (idx < n) offs[idx] = sh[t] - v;   // local exclusive
    if (t == 255) bsum[blockIdx.x] = sh[255];
}

__global__ __launch_bounds__(256) void scan2_k(int* __restrict__ bsum, int nb)
{
    __shared__ int sh[256];
    int t = threadIdx.x;
    int v = (t < nb) ? bsum[t] : 0;
    sh[t] = v;
    __syncthreads();
    for (int o = 1; o < 256; o <<= 1) {
        int a = (t >= o) ? sh[t - o] : 0;
        __syncthreads();
        sh[t] += a;
        __syncthreads();
    }
    if (t < nb) bsum[t] = sh[t] - v;      // exclusive block offsets
}

__global__ __launch_bounds__(256) void scan3_k(
    int* __restrict__ offs, const int* __restrict__ bsum,
    int* __restrict__ cursor, int n, int E)
{
    int idx = blockIdx.x * 256 + threadIdx.x;
    if (idx < n) {
        int o = offs[idx] + bsum[blockIdx.x];
        offs[idx] = o;
        cursor[idx] = o;
    }
    if (idx == 0) offs[n] = E;
}

// scatter: materialize src/ea in dst-sorted order (kills one indirection)
__global__ void scatter_k(const int* __restrict__ dst, const int* __restrict__ src,
                          const float* __restrict__ ea, int* __restrict__ cursor,
                          int* __restrict__ srcS, float* __restrict__ eaS, int E)
{
    int e = blockIdx.x * blockDim.x + threadIdx.x;
    if (e < E) {
        int p = atomicAdd(&cursor[dst[e]], 1);
        srcS[p] = src[e];
        eaS[p] = ea[e];
    }
}

// start[g] = lower_bound(batch, g), g in [0,B]; batch sorted
__global__ void start_k(const int* __restrict__ batch, int* __restrict__ start,
                        int n, int B)
{
    int g = blockIdx.x * blockDim.x + threadIdx.x;
    if (g > B) return;
    int lo = 0, hi = n;
    while (lo < hi) {
        int mid = (lo + hi) >> 1;
        if (batch[mid] < g) lo = mid + 1; else hi = mid;
    }
    start[g] = lo;
}

// ---------------- edge aggregation (one wave per dst node), fp16 I/O ----------
// out[d] = relu(xw[d]+lb) + sum_e relu(xw[srcS]+eaS*we+lb); fp32 accumulate
__global__ __launch_bounds__(256) void aggregate_k(
    const _Float16* __restrict__ xw, const float* __restrict__ we,
    const float* __restrict__ lb, const int* __restrict__ srcS,
    const float* __restrict__ eaS, const int* __restrict__ offs,
    _Float16* __restrict__ out, int n)
{
    int w = (blockIdx.x * blockDim.x + threadIdx.x) >> 6;
    if (w >= n) return;
    int lane = threadIdx.x & 63;
    int f = lane << 2;
    float4 we4 = *(const float4*)(we + f);
    float4 lb4 = *(const float4*)(lb + f);
    f16x4 xs = *(const f16x4*)(xw + (size_t)w * HIDF + f);
    float4 acc;
    acc.x = relu_f((float)xs[0] + lb4.x);
    acc.y = relu_f((float)xs[1] + lb4.y);
    acc.z = relu_f((float)xs[2] + lb4.z);
    acc.w = relu_f((float)xs[3] + lb4.w);
    int e0 = offs[w], e1 = offs[w + 1];
    int ii = e0;
    for (; ii + 4 <= e1; ii += 4) {
        int s0 = srcS[ii], s1 = srcS[ii + 1], s2 = srcS[ii + 2], s3 = srcS[ii + 3];
        float a0 = eaS[ii], a1 = eaS[ii + 1], a2 = eaS[ii + 2], a3 = eaS[ii + 3];
        f16x4 v0 = *(const f16x4*)(xw + (size_t)s0 * HIDF + f);
        f16x4 v1 = *(const f16x4*)(xw + (size_t)s1 * HIDF + f);
        f16x4 v2 = *(const f16x4*)(xw + (size_t)s2 * HIDF + f);
        f16x4 v3 = *(const f16x4*)(xw + (size_t)s3 * HIDF + f);
        acc.x += relu_f(fmaf(a0, we4.x, (float)v0[0]) + lb4.x);
        acc.y += relu_f(fmaf(a0, we4.y, (float)v0[1]) + lb4.y);
        acc.z += relu_f(fmaf(a0, we4.z, (float)v0[2]) + lb4.z);
        acc.w += relu_f(fmaf(a0, we4.w, (float)v0[3]) + lb4.w);
        acc.x += relu_f(fmaf(a1, we4.x, (float)v1[0]) + lb4.x);
        acc.y += relu_f(fmaf(a1, we4.y, (float)v1[1]) + lb4.y);
        acc.z += relu_f(fmaf(a1, we4.z, (float)v1[2]) + lb4.z);
        acc.w += relu_f(fmaf(a1, we4.w, (float)v1[3]) + lb4.w);
        acc.x += relu_f(fmaf(a2, we4.x, (float)v2[0]) + lb4.x);
        acc.y += relu_f(fmaf(a2, we4.y, (float)v2[1]) + lb4.y);
        acc.z += relu_f(fmaf(a2, we4.z, (float)v2[2]) + lb4.z);
        acc.w += relu_f(fmaf(a2, we4.w, (float)v2[3]) + lb4.w);
        acc.x += relu_f(fmaf(a3, we4.x, (float)v3[0]) + lb4.x);
        acc.y += relu_f(fmaf(a3, we4.y, (float)v3[1]) + lb4.y);
        acc.z += relu_f(fmaf(a3, we4.z, (float)v3[2]) + lb4.z);
        acc.w += relu_f(fmaf(a3, we4.w, (float)v3[3]) + lb4.w);
    }
    for (; ii < e1; ++ii) {
        int s0 = srcS[ii];
        float a0 = eaS[ii];
        f16x4 v0 = *(const f16x4*)(xw + (size_t)s0 * HIDF + f);
        acc.x += relu_f(fmaf(a0, we4.x, (float)v0[0]) + lb4.x);
        acc.y += relu_f(fmaf(a0, we4.y, (float)v0[1]) + lb4.y);
        acc.z += relu_f(fmaf(a0, we4.z, (float)v0[2]) + lb4.z);
        acc.w += relu_f(fmaf(a0, we4.w, (float)v0[3]) + lb4.w);
    }
    f16x4 o;
    o[0] = (_Float16)acc.x; o[1] = (_Float16)acc.y;
    o[2] = (_Float16)acc.z; o[3] = (_Float16)acc.w;
    *(f16x4*)(out + (size_t)w * HIDF + f) = o;
}

// ---------------- gate: gate[i] = sigmoid(dot(t[i], g2w) + g2b), t fp16 -------
__global__ __launch_bounds__(256) void gate_k(
    const _Float16* __restrict__ t, const float* __restrict__ g2w,
    const float* __restrict__ g2b, float* __restrict__ gate, int n)
{
    int w = (blockIdx.x * blockDim.x + threadIdx.x) >> 6;
    if (w >= n) return;
    int lane = threadIdx.x & 63;
    f16x4 tv = *(const f16x4*)(t + (size_t)w * HIDF + (lane << 2));
    float4 g = *(const float4*)(g2w + (lane << 2));
    float s = (float)tv[0] * g.x + (float)tv[1] * g.y
            + (float)tv[2] * g.z + (float)tv[3] * g.w;
    for (int o = 32; o; o >>= 1) s += __shfl_xor(s, o);
    if (lane == 0) gate[w] = 1.f / (1.f + expf(-(s + g2b[0])));
}

// ---------------- pooling: pooled[g] = sum_{i in g} x[i]*gate[i], x fp16 ------
__global__ __launch_bounds__(256) void pool_k(
    const _Float16* __restrict__ x, const float* __restrict__ gate,
    const int* __restrict__ start, float* __restrict__ pooled, int B)
{
    int w = (blockIdx.x * blockDim.x + threadIdx.x) >> 6;
    if (w >= B) return;
    int lane = threadIdx.x & 63;
    int f = lane << 2;
    float4 acc = make_float4(0.f, 0.f, 0.f, 0.f);
    int i0 = start[w], i1 = start[w + 1];
    for (int i = i0; i < i1; ++i) {
        float gi = gate[i];
        f16x4 v = *(const f16x4*)(x + (size_t)i * HIDF + f);
        acc.x = fmaf(gi, (float)v[0], acc.x);
        acc.y = fmaf(gi, (float)v[1], acc.y);
        acc.z = fmaf(gi, (float)v[2], acc.z);
        acc.w = fmaf(gi, (float)v[3], acc.w);
    }
    *(float4*)(pooled + (size_t)w * HIDF + f) = acc;
}

// ---------------- fc1: h = [pooled, fp] @ fc1_w + fc1_b ----------------
#define FC1_G 8
#define FC1_K (HIDF + FPDIM)   // 1290
__global__ __launch_bounds__(256) void fc1_k(
    const float* __restrict__ pooled, const float* __restrict__ fp,
    const float* __restrict__ w, const float* __restrict__ b,
    float* __restrict__ h, int B)
{
    __shared__ float in[FC1_G][1292];  // row stride 5168 B (16B aligned)
    int g0 = blockIdx.x * FC1_G;
    int tid = threadIdx.x;
    for (int r = 0; r < FC1_G; ++r) {
        int g = g0 + r;
        in[r][tid] = (g < B) ? pooled[(size_t)g * HIDF + tid] : 0.f;
        for (int c = tid; c < FPDIM; c += 256)
            in[r][HIDF + c] = (g < B) ? fp[(size_t)g * FPDIM + c] : 0.f;
    }
    __syncthreads();
    int j = tid;
    float acc[FC1_G];
#pragma unroll
    for (int r = 0; r < FC1_G; ++r) acc[r] = b[j];
    int k = 0;
    for (; k + 4 <= FC1_K; k += 4) {
        float w0 = w[(size_t)(k + 0) * HIDF + j];
        float w1 = w[(size_t)(k + 1) * HIDF + j];
        float w2 = w[(size_t)(k + 2) * HIDF + j];
        float w3 = w[(size_t)(k + 3) * HIDF + j];
#pragma unroll
        for (int r = 0; r < FC1_G; ++r) {
            float4 iv = *(const float4*)&in[r][k];
            acc[r] = fmaf(iv.x, w0, acc[r]);
            acc[r] = fmaf(iv.y, w1, acc[r]);
            acc[r] = fmaf(iv.z, w2, acc[r]);
            acc[r] = fmaf(iv.w, w3, acc[r]);
        }
    }
    for (; k < FC1_K; ++k) {
        float wk = w[(size_t)k * HIDF + j];
#pragma unroll
        for (int r = 0; r < FC1_G; ++r) acc[r] = fmaf(in[r][k], wk, acc[r]);
    }
    for (int r = 0; r < FC1_G; ++r) {
        int g = g0 + r;
        if (g < B) h[(size_t)g * HIDF + j] = acc[r];
    }
}

// ---------------- BN stats per column ----------------
__global__ __launch_bounds__(256) void bnstats_k(
    const float* __restrict__ h, float* __restrict__ mu,
    float* __restrict__ rs, int B)
{
    int j = blockIdx.x;
    int tid = threadIdx.x;
    float s = 0.f, s2 = 0.f;
    for (int g = tid; g < B; g += 256) {
        float v = h[(size_t)g * HIDF + j];
        s += v;
        s2 = fmaf(v, v, s2);
    }
    __shared__ float sh[256], sh2[256];
    sh[tid] = s; sh2[tid] = s2;
    __syncthreads();
    for (int o = 128; o; o >>= 1) {
        if (tid < o) { sh[tid] += sh[tid + o]; sh2[tid] += sh2[tid + o]; }
        __syncthreads();
    }
    if (tid == 0) {
        float m = sh[0] / (float)B;
        float var = sh2[0] / (float)B - m * m;
        if (var < 0.f) var = 0.f;
        mu[j] = m;
        rs[j] = rsqrtf(var + 1e-5f);
    }
}

// ---------------- final: out[g] = dot(relu(BN(h[g])), fc2w) + fc2b ------------
__global__ __launch_bounds__(256) void final_k(
    const float* __restrict__ h, const float* __restrict__ mu,
    const float* __restrict__ rs, const float* __restrict__ gamma,
    const float* __restrict__ beta, const float* __restrict__ w2,
    const float* __restrict__ b2, float* __restrict__ out, int B)
{
    int g = blockIdx.x;
    int j = threadIdx.x;
    float v = h[(size_t)g * HIDF + j];
    v = (v - mu[j]) * rs[j] * gamma[j] + beta[j];
    v = relu_f(v);
    float term = v * w2[j];
    __shared__ float sh[256];
    sh[j] = term;
    __syncthreads();
    for (int o = 128; o; o >>= 1) {
        if (j < o) sh[j] += sh[j + o];
        __syncthreads();
    }
    if (j == 0) out[g] = sh[0] + b2[0];
}

extern "C" void kernel_launch(void* const* d_in, const int* in_sizes, int n_in,
                              void* d_out, int out_size, void* d_ws, size_t ws_size,
                              hipStream_t stream)
{
    const float* x      = (const float*)d_in[0];
    const int*   ei     = (const int*)d_in[1];
    const float* ea     = (const float*)d_in[2];
    const float* fp     = (const float*)d_in[3];
    const int*   batch  = (const int*)d_in[4];
    const float* lin_w  = (const float*)d_in[5];
    const float* lin_b  = (const float*)d_in[6];
    const float* upd_w  = (const float*)d_in[7];
    const float* upd_b  = (const float*)d_in[8];
    const float* g1w    = (const float*)d_in[9];
    const float* g1b    = (const float*)d_in[10];
    const float* g2w    = (const float*)d_in[11];
    const float* g2b    = (const float*)d_in[12];
    const float* fc1w   = (const float*)d_in[13];
    const float* fc1b   = (const float*)d_in[14];
    const float* gamma  = (const float*)d_in[15];
    const float* beta   = (const float*)d_in[16];
    const float* fc2w   = (const float*)d_in[17];
    const float* fc2b   = (const float*)d_in[18];
    float* out = (float*)d_out;

    const int n = in_sizes[0] / HIDF;        // 50000
    const int E = in_sizes[1] / 2;           // 800000
    const int B = in_sizes[3] / FPDIM;       // 2000
    const int L = in_sizes[5] / (257 * 256); // 4
    const int* srcArr = ei;
    const int* dstArr = ei + E;
    const int nb = (n + 255) / 256;          // scan blocks (196, <=256)

    // ---- workspace layout ----
    char* w = (char*)d_ws;
    _Float16* xh   = (_Float16*)w;  w += (size_t)MPAD * HIDF * 2;   // node state
    _Float16* bufA = (_Float16*)w;  w += (size_t)MPAD * HIDF * 2;   // xw / tanh-out
    _Float16* bufB = (_Float16*)w;  w += (size_t)MPAD * HIDF * 2;   // aggr out
    _Float16* whi = (_Float16*)w;  w += (size_t)9 * 65536 * 2;
    _Float16* wlo = (_Float16*)w;  w += (size_t)9 * 65536 * 2;
    int*   srcS   = (int*)w;    w += (size_t)E * 4;
    float* eaS    = (float*)w;  w += (size_t)E * 4;
    int*   offs   = (int*)w;    w += ((size_t)n + 4) * 4;
    int*   cursor = (int*)w;    w += ((size_t)n + 4) * 4;
    int*   cnt    = (int*)w;    w += (size_t)n * 4;
    int*   bsum   = (int*)w;    w += 256 * 4;
    int*   startA = (int*)w;    w += ((size_t)B + 4) * 4;
    float* gateA  = (float*)w;  w += (size_t)n * 4;
    float* pooled = (float*)w;  w += (size_t)B * HIDF * 4;
    float* h      = (float*)w;  w += (size_t)B * HIDF * 4;
    float* mu     = (float*)w;  w += 256 * 4;
    float* rs     = (float*)w;  w += 256 * 4;

    // ---- CSR build (counting sort by dst) + batch starts ----
    hipMemsetAsync(cnt, 0, (size_t)n * 4, stream);
    count_k<<<(E + 255) / 256, 256, 0, stream>>>(dstArr, cnt, E);
    scan1_k<<<nb, 256, 0, stream>>>(cnt, offs, bsum, n);
    scan2_k<<<1, 256, 0, stream>>>(bsum, nb);
    scan3_k<<<nb, 256, 0, stream>>>(offs, bsum, cursor, n, E);
    scatter_k<<<(E + 255) / 256, 256, 0, stream>>>(dstArr, srcArr, ea, cursor, srcS, eaS, E);
    start_k<<<(B + 256) / 256, 256, 0, stream>>>(batch, startA, n, B);

    // ---- input fp16 conversion + weight split (hi/lo fp16, transposed) ----
    convxh_k<<<(MPAD * 64 + 255) / 256, 256, 0, stream>>>(x, xh, n);
    for (int l = 0; l < L; ++l) {
        convw_k<<<256, 256, 0, stream>>>(lin_w + (size_t)l * 257 * 256,
                                         whi + (size_t)l * 65536, wlo + (size_t)l * 65536);
        convw_k<<<256, 256, 0, stream>>>(upd_w + (size_t)l * 65536,
                                         whi + (size_t)(4 + l) * 65536, wlo + (size_t)(4 + l) * 65536);
    }
    convw_k<<<256, 256, 0, stream>>>(g1w, whi + (size_t)8 * 65536, wlo + (size_t)8 * 65536);

    // ---- message passing: xh -> gemm1 -> bufA -> aggregate -> bufB -> gemm2 -> xh
    dim3 ggm(HIDF / 128, MPAD / 128);
    for (int l = 0; l < L; ++l) {
        const float* we = lin_w + (size_t)l * 257 * 256 + 256 * 256;  // edge row (1x256)
        const float* lb = lin_b + (size_t)l * 256;
        gemm_f16<0><<<ggm, 256, 0, stream>>>(xh, whi + (size_t)l * 65536,
                                             wlo + (size_t)l * 65536, nullptr,
                                             bufA, MPAD, HIDF, HIDF);
        aggregate_k<<<(n * 64 + 255) / 256, 256, 0, stream>>>(
            bufA, we, lb, srcS, eaS, offs, bufB, n);
        gemm_f16<1><<<ggm, 256, 0, stream>>>(bufB, whi + (size_t)(4 + l) * 65536,
                                             wlo + (size_t)(4 + l) * 65536,
                                             upd_b + (size_t)l * 256, xh, MPAD, HIDF, HIDF);
    }

    // ---- gating + pooling ----
    gemm_f16<2><<<ggm, 256, 0, stream>>>(xh, whi + (size_t)8 * 65536,
                                         wlo + (size_t)8 * 65536, g1b,
                                         bufA, MPAD, HIDF, HIDF);
    gate_k<<<(n * 64 + 255) / 256, 256, 0, stream>>>(bufA, g2w, g2b, gateA, n);
    pool_k<<<(B * 64 + 255) / 256, 256, 0, stream>>>(xh, gateA, startA, pooled, B);

    // ---- head (fp32) ----
    fc1_k<<<(B + FC1_G - 1) / FC1_G, 256, 0, stream>>>(pooled, fp, fc1w, fc1b, h, B);
    bnstats_k<<<256, 256, 0, stream>>>(h, mu, rs, B);
    final_k<<<B, 256, 0, stream>>>(h, mu, rs, gamma, beta, fc2w, fc2b, out, B);
}

// Round 6
// 717.537 us; speedup vs baseline: 2.5751x; 1.0186x over previous
//
#include <hip/hip_runtime.h>
#include <math.h>

#define HIDF 256
#define FPDIM 1034
#define MPAD 50048     // 50000 rounded up to 128
#define FCM 2048       // fc1 M pad (B=2000)
#define FCK 1344       // fc1 K pad (1290 -> 21*64)

typedef _Float16 f16x8 __attribute__((ext_vector_type(8)));
typedef _Float16 f16x4 __attribute__((ext_vector_type(4)));
typedef float f32x4 __attribute__((ext_vector_type(4)));

__device__ __forceinline__ float relu_f(float v) { return fmaxf(v, 0.f); }

// ---------------- x fp32 -> fp16 [MPAD][256], zero pad ----------------
__global__ __launch_bounds__(256) void convxh_k(
    const float* __restrict__ x, _Float16* __restrict__ xh, int n)
{
    int i = blockIdx.x * 256 + threadIdx.x;   // 4-elem group index
    int row = i >> 6;
    if (row >= MPAD) return;
    f16x4 o;
    if (row < n) {
        float4 v = ((const float4*)x)[i];
        o[0] = (_Float16)v.x; o[1] = (_Float16)v.y;
        o[2] = (_Float16)v.z; o[3] = (_Float16)v.w;
    } else {
        o[0] = o[1] = o[2] = o[3] = (_Float16)0.f;
    }
    ((f16x4*)xh)[i] = o;
}

// ------- weight: W fp32 [K=256][N=256] -> W^T split fp16 hi/lo [N][K] --------
__global__ __launch_bounds__(256) void convw_k(
    const float* __restrict__ w, _Float16* __restrict__ whi,
    _Float16* __restrict__ wlo)
{
    int i = blockIdx.x * 256 + threadIdx.x;   // 0..65535
    int nn = i >> 8, kk = i & 255;
    float v = w[kk * 256 + nn];
    _Float16 h = (_Float16)v;
    _Float16 l = (_Float16)(v - (float)h);
    whi[i] = h;
    wlo[i] = l;
}

// ------- fc1 input: [pooled | fp] -> split fp16 hi/lo [FCM][FCK] --------------
__global__ __launch_bounds__(256) void convfc1a_k(
    const float* __restrict__ pooled, const float* __restrict__ fp,
    _Float16* __restrict__ ahi, _Float16* __restrict__ alo, int B)
{
    int i = blockIdx.x * 256 + threadIdx.x;
    if (i >= FCM * FCK) return;
    int row = i / FCK, col = i - row * FCK;
    float v = 0.f;
    if (row < B) {
        if (col < HIDF) v = pooled[(size_t)row * HIDF + col];
        else if (col < HIDF + FPDIM) v = fp[(size_t)row * FPDIM + (col - HIDF)];
    }
    _Float16 h = (_Float16)v;
    _Float16 l = (_Float16)(v - (float)h);
    ahi[i] = h;
    alo[i] = l;
}

// ------- fc1 weight: [1290][256] -> W^T split fp16 hi/lo [256][FCK] -----------
__global__ __launch_bounds__(256) void convfc1w_k(
    const float* __restrict__ w, _Float16* __restrict__ whi,
    _Float16* __restrict__ wlo)
{
    int i = blockIdx.x * 256 + threadIdx.x;
    if (i >= HIDF * FCK) return;
    int nn = i / FCK, kk = i - nn * FCK;
    float v = (kk < HIDF + FPDIM) ? w[(size_t)kk * HIDF + nn] : 0.f;
    _Float16 h = (_Float16)v;
    _Float16 l = (_Float16)(v - (float)h);
    whi[i] = h;
    wlo[i] = l;
}

// ---------------- fp16 MFMA GEMM: C = act(A @ W^T + bias), fp16 out -----------
// A: [M][K] fp16 row-major (M mult of 128). Whi/Wlo: [N][K] fp16 row-major.
// BM=BN=128, BK=64, 4 waves (2x2 of 64x64), mfma_f32_16x16x32_f16.
// acc = A*Whi + A*Wlo (weights ~22-bit effective; A fp16-exact)
// ACT: 0 none, 1 relu, 2 tanh.
template <int ACT>
__global__ __launch_bounds__(256) void gemm_f16(
    const _Float16* __restrict__ A, const _Float16* __restrict__ Whi,
    const _Float16* __restrict__ Wlo, const float* __restrict__ bias,
    _Float16* __restrict__ C, int M, int N, int K)
{
    __shared__ _Float16 As[128 * 64];
    __shared__ _Float16 Bh[128 * 64];
    __shared__ _Float16 Bl[128 * 64];
    const int tid = threadIdx.x;
    const int wave = tid >> 6, lane = tid & 63;
    const int m0 = blockIdx.y * 128, n0 = blockIdx.x * 128;
    const int wr = wave >> 1, wc = wave & 1;

    f32x4 acc[4][4];
#pragma unroll
    for (int i = 0; i < 4; ++i)
#pragma unroll
        for (int j = 0; j < 4; ++j) acc[i][j] = (f32x4){0.f, 0.f, 0.f, 0.f};

    const int lrow = lane >> 3;           // 0..7
    const int lcol8 = (lane & 7) * 8;

    for (int k0 = 0; k0 < K; k0 += 64) {
#pragma unroll
        for (int i = 0; i < 4; ++i) {
            int iss = wave * 4 + i;       // 0..15, each covers 8 rows (1 KiB)
            int row = 8 * iss + lrow;
            const _Float16* ga = A   + (size_t)(m0 + row) * K + k0 + lcol8;
            const _Float16* gh = Whi + (size_t)(n0 + row) * K + k0 + lcol8;
            const _Float16* gl = Wlo + (size_t)(n0 + row) * K + k0 + lcol8;
            __builtin_amdgcn_global_load_lds(
                (const __attribute__((address_space(1))) void*)ga,
                (__attribute__((address_space(3))) void*)(As + iss * 512), 16, 0, 0);
            __builtin_amdgcn_global_load_lds(
                (const __attribute__((address_space(1))) void*)gh,
                (__attribute__((address_space(3))) void*)(Bh + iss * 512), 16, 0, 0);
            __builtin_amdgcn_global_load_lds(
                (const __attribute__((address_space(1))) void*)gl,
                (__attribute__((address_space(3))) void*)(Bl + iss * 512), 16, 0, 0);
        }
        __syncthreads();
#pragma unroll
        for (int kk = 0; kk < 2; ++kk) {
            const int kb = kk * 32 + (lane >> 4) * 8;
            f16x8 af[4], bh[4], bl[4];
#pragma unroll
            for (int mi = 0; mi < 4; ++mi)
                af[mi] = *(const f16x8*)&As[(wr * 64 + mi * 16 + (lane & 15)) * 64 + kb];
#pragma unroll
            for (int ni = 0; ni < 4; ++ni) {
                int r = (wc * 64 + ni * 16 + (lane & 15)) * 64 + kb;
                bh[ni] = *(const f16x8*)&Bh[r];
                bl[ni] = *(const f16x8*)&Bl[r];
            }
#pragma unroll
            for (int mi = 0; mi < 4; ++mi)
#pragma unroll
                for (int ni = 0; ni < 4; ++ni) {
                    acc[mi][ni] = __builtin_amdgcn_mfma_f32_16x16x32_f16(
                        af[mi], bh[ni], acc[mi][ni], 0, 0, 0);
                    acc[mi][ni] = __builtin_amdgcn_mfma_f32_16x16x32_f16(
                        af[mi], bl[ni], acc[mi][ni], 0, 0, 0);
                }
        }
        __syncthreads();
    }

    const int crow0 = m0 + wr * 64 + (lane >> 4) * 4;
    const int ccol0 = n0 + wc * 64 + (lane & 15);
#pragma unroll
    for (int mi = 0; mi < 4; ++mi) {
#pragma unroll
        for (int ni = 0; ni < 4; ++ni) {
            int col = ccol0 + ni * 16;
            float bv = bias ? bias[col] : 0.f;
#pragma unroll
            for (int r = 0; r < 4; ++r) {
                int row = crow0 + mi * 16 + r;
                float v = acc[mi][ni][r] + bv;
                if (ACT == 1) v = relu_f(v);
                else if (ACT == 2) v = tanhf(v);
                C[(size_t)row * N + col] = (_Float16)v;
            }
        }
    }
}

// ---------------- fc1 MFMA GEMM (3-term split, fp32 out) ----------------------
// Ahi/Alo: [FCM][FCK] fp16; Whi/Wlo: [N][FCK] fp16. acc = Ah*Bh + Ah*Bl + Al*Bh.
__global__ __launch_bounds__(256) void gemm_fc1(
    const _Float16* __restrict__ Ahi, const _Float16* __restrict__ Alo,
    const _Float16* __restrict__ Whi, const _Float16* __restrict__ Wlo,
    const float* __restrict__ bias, float* __restrict__ C,
    int Mv, int N, int K)
{
    __shared__ _Float16 Ah[128 * 64];
    __shared__ _Float16 Al[128 * 64];
    __shared__ _Float16 Bh[128 * 64];
    __shared__ _Float16 Bl[128 * 64];
    const int tid = threadIdx.x;
    const int wave = tid >> 6, lane = tid & 63;
    const int m0 = blockIdx.y * 128, n0 = blockIdx.x * 128;
    const int wr = wave >> 1, wc = wave & 1;

    f32x4 acc[4][4];
#pragma unroll
    for (int i = 0; i < 4; ++i)
#pragma unroll
        for (int j = 0; j < 4; ++j) acc[i][j] = (f32x4){0.f, 0.f, 0.f, 0.f};

    const int lrow = lane >> 3;
    const int lcol8 = (lane & 7) * 8;

    for (int k0 = 0; k0 < K; k0 += 64) {
#pragma unroll
        for (int i = 0; i < 4; ++i) {
            int iss = wave * 4 + i;
            int row = 8 * iss + lrow;
            const _Float16* gah = Ahi + (size_t)(m0 + row) * K + k0 + lcol8;
            const _Float16* gal = Alo + (size_t)(m0 + row) * K + k0 + lcol8;
            const _Float16* gbh = Whi + (size_t)(n0 + row) * K + k0 + lcol8;
            const _Float16* gbl = Wlo + (size_t)(n0 + row) * K + k0 + lcol8;
            __builtin_amdgcn_global_load_lds(
                (const __attribute__((address_space(1))) void*)gah,
                (__attribute__((address_space(3))) void*)(Ah + iss * 512), 16, 0, 0);
            __builtin_amdgcn_global_load_lds(
                (const __attribute__((address_space(1))) void*)gal,
                (__attribute__((address_space(3))) void*)(Al + iss * 512), 16, 0, 0);
            __builtin_amdgcn_global_load_lds(
                (const __attribute__((address_space(1))) void*)gbh,
                (__attribute__((address_space(3))) void*)(Bh + iss * 512), 16, 0, 0);
            __builtin_amdgcn_global_load_lds(
                (const __attribute__((address_space(1))) void*)gbl,
                (__attribute__((address_space(3))) void*)(Bl + iss * 512), 16, 0, 0);
        }
        __syncthreads();
#pragma unroll
        for (int kk = 0; kk < 2; ++kk) {
            const int kb = kk * 32 + (lane >> 4) * 8;
            f16x8 ah[4], al[4], bh[4], bl[4];
#pragma unroll
            for (int mi = 0; mi < 4; ++mi) {
                int r = (wr * 64 + mi * 16 + (lane & 15)) * 64 + kb;
                ah[mi] = *(const f16x8*)&Ah[r];
                al[mi] = *(const f16x8*)&Al[r];
            }
#pragma unroll
            for (int ni = 0; ni < 4; ++ni) {
                int r = (wc * 64 + ni * 16 + (lane & 15)) * 64 + kb;
                bh[ni] = *(const f16x8*)&Bh[r];
                bl[ni] = *(const f16x8*)&Bl[r];
            }
#pragma unroll
            for (int mi = 0; mi < 4; ++mi)
#pragma unroll
                for (int ni = 0; ni < 4; ++ni) {
                    acc[mi][ni] = __builtin_amdgcn_mfma_f32_16x16x32_f16(
                        ah[mi], bh[ni], acc[mi][ni], 0, 0, 0);
                    acc[mi][ni] = __builtin_amdgcn_mfma_f32_16x16x32_f16(
                        ah[mi], bl[ni], acc[mi][ni], 0, 0, 0);
                    acc[mi][ni] = __builtin_amdgcn_mfma_f32_16x16x32_f16(
                        al[mi], bh[ni], acc[mi][ni], 0, 0, 0);
                }
        }
        __syncthreads();
    }

    const int crow0 = m0 + wr * 64 + (lane >> 4) * 4;
    const int ccol0 = n0 + wc * 64 + (lane & 15);
#pragma unroll
    for (int mi = 0; mi < 4; ++mi) {
#pragma unroll
        for (int ni = 0; ni < 4; ++ni) {
            int col = ccol0 + ni * 16;
            float bv = bias[col];
#pragma unroll
            for (int r = 0; r < 4; ++r) {
                int row = crow0 + mi * 16 + r;
                if (row < Mv)
                    C[(size_t)row * N + col] = acc[mi][ni][r] + bv;
            }
        }
    }
}

// ---------------- counting sort of edges by dst ----------------
__global__ void count_k(const int* __restrict__ dst, int* __restrict__ cnt, int E)
{
    int e = blockIdx.x * blockDim.x + threadIdx.x;
    if (e < E) atomicAdd(&cnt[dst[e]], 1);
}

// 3-phase exclusive scan of cnt[n]
__global__ __launch_bounds__(256) void scan1_k(
    const int* __restrict__ cnt, int* __restrict__ offs,
    int* __restrict__ bsum, int n)
{
    __shared__ int sh[256];
    int t = threadIdx.x, idx = blockIdx.x * 256 + t;
    int v = (idx < n) ? cnt[idx] : 0;
    sh[t] = v;
    __syncthreads();
    for (int o = 1; o < 256; o <<= 1) {
        int a = (t >= o) ? sh[t - o] : 0;
        __syncthreads();
        sh[t] += a;
        __syncthreads();
    }
    if (idx < n) offs[idx] = sh[t] - v;
    if (t == 255) bsum[blockIdx.x] = sh[255];
}

__global__ __launch_bounds__(256) void scan2_k(int* __restrict__ bsum, int nb)
{
    __shared__ int sh[256];
    int t = threadIdx.x;
    int v = (t < nb) ? bsum[t] : 0;
    sh[t] = v;
    __syncthreads();
    for (int o = 1; o < 256; o <<= 1) {
        int a = (t >= o) ? sh[t - o] : 0;
        __syncthreads();
        sh[t] += a;
        __syncthreads();
    }
    if (t < nb) bsum[t] = sh[t] - v;
}

__global__ __launch_bounds__(256) void scan3_k(
    int* __restrict__ offs, const int* __restrict__ bsum,
    int* __restrict__ cursor, int n, int E)
{
    int idx = blockIdx.x * 256 + threadIdx.x;
    if (idx < n) {
        int o = offs[idx] + bsum[blockIdx.x];
        offs[idx] = o;
        cursor[idx] = o;
    }
    if (idx == 0) offs[n] = E;
}

__global__ void scatter_k(const int* __restrict__ dst, const int* __restrict__ src,
                          const float* __restrict__ ea, int* __restrict__ cursor,
                          int* __restrict__ srcS, float* __restrict__ eaS, int E)
{
    int e = blockIdx.x * blockDim.x + threadIdx.x;
    if (e < E) {
        int p = atomicAdd(&cursor[dst[e]], 1);
        srcS[p] = src[e];
        eaS[p] = ea[e];
    }
}

// start[g] = lower_bound(batch, g)
__global__ void start_k(const int* __restrict__ batch, int* __restrict__ start,
                        int n, int B)
{
    int g = blockIdx.x * blockDim.x + threadIdx.x;
    if (g > B) return;
    int lo = 0, hi = n;
    while (lo < hi) {
        int mid = (lo + hi) >> 1;
        if (batch[mid] < g) lo = mid + 1; else hi = mid;
    }
    start[g] = lo;
}

// ---------------- edge aggregation (one wave per dst node), fp16 I/O ----------
// lb pre-folded into xw (gemm1 bias): out[d] = relu(xw[d]) + sum_e relu(xw[src]+ea*we)
__global__ __launch_bounds__(256) void aggregate_k(
    const _Float16* __restrict__ xw, const float* __restrict__ we,
    const int* __restrict__ srcS, const float* __restrict__ eaS,
    const int* __restrict__ offs, _Float16* __restrict__ out, int n)
{
    int w = (blockIdx.x * blockDim.x + threadIdx.x) >> 6;
    if (w >= n) return;
    int lane = threadIdx.x & 63;
    int f = lane << 2;
    float4 we4 = *(const float4*)(we + f);
    f16x4 xs = *(const f16x4*)(xw + (size_t)w * HIDF + f);
    float4 acc;
    acc.x = relu_f((float)xs[0]);
    acc.y = relu_f((float)xs[1]);
    acc.z = relu_f((float)xs[2]);
    acc.w = relu_f((float)xs[3]);
    int e0 = offs[w], e1 = offs[w + 1];
    int ii = e0;
    for (; ii + 8 <= e1; ii += 8) {
        int s[8]; float a[8]; f16x4 v[8];
#pragma unroll
        for (int j = 0; j < 8; ++j) { s[j] = srcS[ii + j]; a[j] = eaS[ii + j]; }
#pragma unroll
        for (int j = 0; j < 8; ++j)
            v[j] = *(const f16x4*)(xw + (size_t)s[j] * HIDF + f);
#pragma unroll
        for (int j = 0; j < 8; ++j) {
            acc.x += relu_f(fmaf(a[j], we4.x, (float)v[j][0]));
            acc.y += relu_f(fmaf(a[j], we4.y, (float)v[j][1]));
            acc.z += relu_f(fmaf(a[j], we4.z, (float)v[j][2]));
            acc.w += relu_f(fmaf(a[j], we4.w, (float)v[j][3]));
        }
    }
    if (ii + 4 <= e1) {
        int s[4]; float a[4]; f16x4 v[4];
#pragma unroll
        for (int j = 0; j < 4; ++j) { s[j] = srcS[ii + j]; a[j] = eaS[ii + j]; }
#pragma unroll
        for (int j = 0; j < 4; ++j)
            v[j] = *(const f16x4*)(xw + (size_t)s[j] * HIDF + f);
#pragma unroll
        for (int j = 0; j < 4; ++j) {
            acc.x += relu_f(fmaf(a[j], we4.x, (float)v[j][0]));
            acc.y += relu_f(fmaf(a[j], we4.y, (float)v[j][1]));
            acc.z += relu_f(fmaf(a[j], we4.z, (float)v[j][2]));
            acc.w += relu_f(fmaf(a[j], we4.w, (float)v[j][3]));
        }
        ii += 4;
    }
    for (; ii < e1; ++ii) {
        int s0 = srcS[ii];
        float a0 = eaS[ii];
        f16x4 v0 = *(const f16x4*)(xw + (size_t)s0 * HIDF + f);
        acc.x += relu_f(fmaf(a0, we4.x, (float)v0[0]));
        acc.y += relu_f(fmaf(a0, we4.y, (float)v0[1]));
        acc.z += relu_f(fmaf(a0, we4.z, (float)v0[2]));
        acc.w += relu_f(fmaf(a0, we4.w, (float)v0[3]));
    }
    f16x4 o;
    o[0] = (_Float16)acc.x; o[1] = (_Float16)acc.y;
    o[2] = (_Float16)acc.z; o[3] = (_Float16)acc.w;
    *(f16x4*)(out + (size_t)w * HIDF + f) = o;
}

// ---------------- gate: gate[i] = sigmoid(dot(t[i], g2w) + g2b) ---------------
__global__ __launch_bounds__(256) void gate_k(
    const _Float16* __restrict__ t, const float* __restrict__ g2w,
    const float* __restrict__ g2b, float* __restrict__ gate, int n)
{
    int w = (blockIdx.x * blockDim.x + threadIdx.x) >> 6;
    if (w >= n) return;
    int lane = threadIdx.x & 63;
    f16x4 tv = *(const f16x4*)(t + (size_t)w * HIDF + (lane << 2));
    float4 g = *(const float4*)(g2w + (lane << 2));
    float s = (float)tv[0] * g.x + (float)tv[1] * g.y
            + (float)tv[2] * g.z + (float)tv[3] * g.w;
    for (int o = 32; o; o >>= 1) s += __shfl_xor(s, o);
    if (lane == 0) gate[w] = 1.f / (1.f + expf(-(s + g2b[0])));
}

// ---------------- pooling ----------------
__global__ __launch_bounds__(256) void pool_k(
    const _Float16* __restrict__ x, const float* __restrict__ gate,
    const int* __restrict__ start, float* __restrict__ pooled, int B)
{
    int w = (blockIdx.x * blockDim.x + threadIdx.x) >> 6;
    if (w >= B) return;
    int lane = threadIdx.x & 63;
    int f = lane << 2;
    float4 acc = make_float4(0.f, 0.f, 0.f, 0.f);
    int i0 = start[w], i1 = start[w + 1];
    for (int i = i0; i < i1; ++i) {
        float gi = gate[i];
        f16x4 v = *(const f16x4*)(x + (size_t)i * HIDF + f);
        acc.x = fmaf(gi, (float)v[0], acc.x);
        acc.y = fmaf(gi, (float)v[1], acc.y);
        acc.z = fmaf(gi, (float)v[2], acc.z);
        acc.w = fmaf(gi, (float)v[3], acc.w);
    }
    *(float4*)(pooled + (size_t)w * HIDF + f) = acc;
}

// ---------------- BN stats per column ----------------
__global__ __launch_bounds__(256) void bnstats_k(
    const float* __restrict__ h, float* __restrict__ mu,
    float* __restrict__ rs, int B)
{
    int j = blockIdx.x;
    int tid = threadIdx.x;
    float s = 0.f, s2 = 0.f;
    for (int g = tid; g < B; g += 256) {
        float v = h[(size_t)g * HIDF + j];
        s += v;
        s2 = fmaf(v, v, s2);
    }
    __shared__ float sh[256], sh2[256];
    sh[tid] = s; sh2[tid] = s2;
    __syncthreads();
    for (int o = 128; o; o >>= 1) {
        if (tid < o) { sh[tid] += sh[tid + o]; sh2[tid] += sh2[tid + o]; }
        __syncthreads();
    }
    if (tid == 0) {
        float m = sh[0] / (float)B;
        float var = sh2[0] / (float)B - m * m;
        if (var < 0.f) var = 0.f;
        mu[j] = m;
        rs[j] = rsqrtf(var + 1e-5f);
    }
}

// ---------------- final ----------------
__global__ __launch_bounds__(256) void final_k(
    const float* __restrict__ h, const float* __restrict__ mu,
    const float* __restrict__ rs, const float* __restrict__ gamma,
    const float* __restrict__ beta, const float* __restrict__ w2,
    const float* __restrict__ b2, float* __restrict__ out, int B)
{
    int g = blockIdx.x;
    int j = threadIdx.x;
    float v = h[(size_t)g * HIDF + j];
    v = (v - mu[j]) * rs[j] * gamma[j] + beta[j];
    v = relu_f(v);
    float term = v * w2[j];
    __shared__ float sh[256];
    sh[j] = term;
    __syncthreads();
    for (int o = 128; o; o >>= 1) {
        if (j < o) sh[j] += sh[j + o];
        __syncthreads();
    }
    if (j == 0) out[g] = sh[0] + b2[0];
}

extern "C" void kernel_launch(void* const* d_in, const int* in_sizes, int n_in,
                              void* d_out, int out_size, void* d_ws, size_t ws_size,
                              hipStream_t stream)
{
    const float* x      = (const float*)d_in[0];
    const int*   ei     = (const int*)d_in[1];
    const float* ea     = (const float*)d_in[2];
    const float* fp     = (const float*)d_in[3];
    const int*   batch  = (const int*)d_in[4];
    const float* lin_w  = (const float*)d_in[5];
    const float* lin_b  = (const float*)d_in[6];
    const float* upd_w  = (const float*)d_in[7];
    const float* upd_b  = (const float*)d_in[8];
    const float* g1w    = (const float*)d_in[9];
    const float* g1b    = (const float*)d_in[10];
    const float* g2w    = (const float*)d_in[11];
    const float* g2b    = (const float*)d_in[12];
    const float* fc1w   = (const float*)d_in[13];
    const float* fc1b   = (const float*)d_in[14];
    const float* gamma  = (const float*)d_in[15];
    const float* beta   = (const float*)d_in[16];
    const float* fc2w   = (const float*)d_in[17];
    const float* fc2b   = (const float*)d_in[18];
    float* out = (float*)d_out;

    const int n = in_sizes[0] / HIDF;        // 50000
    const int E = in_sizes[1] / 2;           // 800000
    const int B = in_sizes[3] / FPDIM;       // 2000
    const int L = in_sizes[5] / (257 * 256); // 4
    const int* srcArr = ei;
    const int* dstArr = ei + E;
    const int nb = (n + 255) / 256;

    // ---- workspace layout ----
    char* w = (char*)d_ws;
    _Float16* xh   = (_Float16*)w;  w += (size_t)MPAD * HIDF * 2;   // node state
    _Float16* bufA = (_Float16*)w;  w += (size_t)MPAD * HIDF * 2;   // xw / tanh-out
    _Float16* bufB = (_Float16*)w;  w += (size_t)MPAD * HIDF * 2;   // aggr out
    _Float16* whi = (_Float16*)w;  w += (size_t)9 * 65536 * 2;
    _Float16* wlo = (_Float16*)w;  w += (size_t)9 * 65536 * 2;
    _Float16* fahi = (_Float16*)w; w += (size_t)FCM * FCK * 2;
    _Float16* falo = (_Float16*)w; w += (size_t)FCM * FCK * 2;
    _Float16* fwhi = (_Float16*)w; w += (size_t)HIDF * FCK * 2;
    _Float16* fwlo = (_Float16*)w; w += (size_t)HIDF * FCK * 2;
    int*   srcS   = (int*)w;    w += (size_t)E * 4;
    float* eaS    = (float*)w;  w += (size_t)E * 4;
    int*   offs   = (int*)w;    w += ((size_t)n + 4) * 4;
    int*   cursor = (int*)w;    w += ((size_t)n + 4) * 4;
    int*   cnt    = (int*)w;    w += (size_t)n * 4;
    int*   bsum   = (int*)w;    w += 256 * 4;
    int*   startA = (int*)w;    w += ((size_t)B + 4) * 4;
    float* gateA  = (float*)w;  w += (size_t)n * 4;
    float* pooled = (float*)w;  w += (size_t)B * HIDF * 4;
    float* h      = (float*)w;  w += (size_t)B * HIDF * 4;
    float* mu     = (float*)w;  w += 256 * 4;
    float* rs     = (float*)w;  w += 256 * 4;

    // ---- CSR build (counting sort by dst) + batch starts ----
    hipMemsetAsync(cnt, 0, (size_t)n * 4, stream);
    count_k<<<(E + 255) / 256, 256, 0, stream>>>(dstArr, cnt, E);
    scan1_k<<<nb, 256, 0, stream>>>(cnt, offs, bsum, n);
    scan2_k<<<1, 256, 0, stream>>>(bsum, nb);
    scan3_k<<<nb, 256, 0, stream>>>(offs, bsum, cursor, n, E);
    scatter_k<<<(E + 255) / 256, 256, 0, stream>>>(dstArr, srcArr, ea, cursor, srcS, eaS, E);
    start_k<<<(B + 256) / 256, 256, 0, stream>>>(batch, startA, n, B);

    // ---- input fp16 conversion + weight split ----
    convxh_k<<<(MPAD * 64 + 255) / 256, 256, 0, stream>>>(x, xh, n);
    for (int l = 0; l < L; ++l) {
        convw_k<<<256, 256, 0, stream>>>(lin_w + (size_t)l * 257 * 256,
                                         whi + (size_t)l * 65536, wlo + (size_t)l * 65536);
        convw_k<<<256, 256, 0, stream>>>(upd_w + (size_t)l * 65536,
                                         whi + (size_t)(4 + l) * 65536, wlo + (size_t)(4 + l) * 65536);
    }
    convw_k<<<256, 256, 0, stream>>>(g1w, whi + (size_t)8 * 65536, wlo + (size_t)8 * 65536);
    convfc1w_k<<<(HIDF * FCK + 255) / 256, 256, 0, stream>>>(fc1w, fwhi, fwlo);

    // ---- message passing: xh -> gemm1(+lb) -> bufA -> aggregate -> bufB -> gemm2 -> xh
    dim3 ggm(HIDF / 128, MPAD / 128);
    for (int l = 0; l < L; ++l) {
        const float* we = lin_w + (size_t)l * 257 * 256 + 256 * 256;  // edge row (1x256)
        const float* lb = lin_b + (size_t)l * 256;
        gemm_f16<0><<<ggm, 256, 0, stream>>>(xh, whi + (size_t)l * 65536,
                                             wlo + (size_t)l * 65536, lb,
                                             bufA, MPAD, HIDF, HIDF);
        aggregate_k<<<(n * 64 + 255) / 256, 256, 0, stream>>>(
            bufA, we, srcS, eaS, offs, bufB, n);
        gemm_f16<1><<<ggm, 256, 0, stream>>>(bufB, whi + (size_t)(4 + l) * 65536,
                                             wlo + (size_t)(4 + l) * 65536,
                                             upd_b + (size_t)l * 256, xh, MPAD, HIDF, HIDF);
    }

    // ---- gating + pooling ----
    gemm_f16<2><<<ggm, 256, 0, stream>>>(xh, whi + (size_t)8 * 65536,
                                         wlo + (size_t)8 * 65536, g1b,
                                         bufA, MPAD, HIDF, HIDF);
    gate_k<<<(n * 64 + 255) / 256, 256, 0, stream>>>(bufA, g2w, g2b, gateA, n);
    pool_k<<<(B * 64 + 255) / 256, 256, 0, stream>>>(xh, gateA, startA, pooled, B);

    // ---- head: fc1 via 3-term split MFMA, then BN + final (fp32) ----
    convfc1a_k<<<(FCM * FCK + 255) / 256, 256, 0, stream>>>(pooled, fp, fahi, falo, B);
    dim3 ggf(HIDF / 128, FCM / 128);
    gemm_fc1<<<ggf, 256, 0, stream>>>(fahi, falo, fwhi, fwlo, fc1b, h, B, HIDF, FCK);
    bnstats_k<<<256, 256, 0, stream>>>(h, mu, rs, B);
    final_k<<<B, 256, 0, stream>>>(h, mu, rs, gamma, beta, fc2w, fc2b, out, B);
}

// Round 7
// 713.962 us; speedup vs baseline: 2.5880x; 1.0050x over previous
//
#include <hip/hip_runtime.h>
#include <math.h>

#define HIDF 256
#define FPDIM 1034
#define MPAD 50048     // 50000 rounded up to 128
#define FCM 2048       // fc1 M pad (B=2000)
#define FCK 1344       // fc1 K pad (1290 -> 21*64)

typedef _Float16 f16x8 __attribute__((ext_vector_type(8)));
typedef _Float16 f16x4 __attribute__((ext_vector_type(4)));
typedef float f32x4 __attribute__((ext_vector_type(4)));

__device__ __forceinline__ float relu_f(float v) { return fmaxf(v, 0.f); }

// ---------------- x fp32 -> fp16 [MPAD][256], zero pad ----------------
__global__ __launch_bounds__(256) void convxh_k(
    const float* __restrict__ x, _Float16* __restrict__ xh, int n)
{
    int i = blockIdx.x * 256 + threadIdx.x;   // 4-elem group index
    int row = i >> 6;
    if (row >= MPAD) return;
    f16x4 o;
    if (row < n) {
        float4 v = ((const float4*)x)[i];
        o[0] = (_Float16)v.x; o[1] = (_Float16)v.y;
        o[2] = (_Float16)v.z; o[3] = (_Float16)v.w;
    } else {
        o[0] = o[1] = o[2] = o[3] = (_Float16)0.f;
    }
    ((f16x4*)xh)[i] = o;
}

// ------- weight: W fp32 [K=256][N=256] -> W^T split fp16 hi/lo [N][K] --------
__global__ __launch_bounds__(256) void convw_k(
    const float* __restrict__ w, _Float16* __restrict__ whi,
    _Float16* __restrict__ wlo)
{
    int i = blockIdx.x * 256 + threadIdx.x;   // 0..65535
    int nn = i >> 8, kk = i & 255;
    float v = w[kk * 256 + nn];
    _Float16 h = (_Float16)v;
    _Float16 l = (_Float16)(v - (float)h);
    whi[i] = h;
    wlo[i] = l;
}

// ------- fc1 input: [pooled | fp] -> split fp16 hi/lo [FCM][FCK] --------------
__global__ __launch_bounds__(256) void convfc1a_k(
    const float* __restrict__ pooled, const float* __restrict__ fp,
    _Float16* __restrict__ ahi, _Float16* __restrict__ alo, int B)
{
    int i = blockIdx.x * 256 + threadIdx.x;
    if (i >= FCM * FCK) return;
    int row = i / FCK, col = i - row * FCK;
    float v = 0.f;
    if (row < B) {
        if (col < HIDF) v = pooled[(size_t)row * HIDF + col];
        else if (col < HIDF + FPDIM) v = fp[(size_t)row * FPDIM + (col - HIDF)];
    }
    _Float16 h = (_Float16)v;
    _Float16 l = (_Float16)(v - (float)h);
    ahi[i] = h;
    alo[i] = l;
}

// ------- fc1 weight: [1290][256] -> W^T split fp16 hi/lo [256][FCK] -----------
__global__ __launch_bounds__(256) void convfc1w_k(
    const float* __restrict__ w, _Float16* __restrict__ whi,
    _Float16* __restrict__ wlo)
{
    int i = blockIdx.x * 256 + threadIdx.x;
    if (i >= HIDF * FCK) return;
    int nn = i / FCK, kk = i - nn * FCK;
    float v = (kk < HIDF + FPDIM) ? w[(size_t)kk * HIDF + nn] : 0.f;
    _Float16 h = (_Float16)v;
    _Float16 l = (_Float16)(v - (float)h);
    whi[i] = h;
    wlo[i] = l;
}

// ---------------- fp16 MFMA GEMM: C = act(A @ W^T + bias), fp16 out -----------
// A: [M][K] fp16 row-major (M mult of 128). Whi/Wlo: [N][K] fp16 row-major.
// BM=BN=128, BK=64, 4 waves (2x2 of 64x64), mfma_f32_16x16x32_f16.
// acc = A*Whi + A*Wlo (weights ~22-bit effective; A fp16-exact)
// ACT: 0 none, 1 relu, 2 tanh.
template <int ACT>
__global__ __launch_bounds__(256) void gemm_f16(
    const _Float16* __restrict__ A, const _Float16* __restrict__ Whi,
    const _Float16* __restrict__ Wlo, const float* __restrict__ bias,
    _Float16* __restrict__ C, int M, int N, int K)
{
    __shared__ _Float16 As[128 * 64];
    __shared__ _Float16 Bh[128 * 64];
    __shared__ _Float16 Bl[128 * 64];
    const int tid = threadIdx.x;
    const int wave = tid >> 6, lane = tid & 63;
    const int m0 = blockIdx.y * 128, n0 = blockIdx.x * 128;
    const int wr = wave >> 1, wc = wave & 1;

    f32x4 acc[4][4];
#pragma unroll
    for (int i = 0; i < 4; ++i)
#pragma unroll
        for (int j = 0; j < 4; ++j) acc[i][j] = (f32x4){0.f, 0.f, 0.f, 0.f};

    const int lrow = lane >> 3;           // 0..7
    const int lcol8 = (lane & 7) * 8;

    for (int k0 = 0; k0 < K; k0 += 64) {
#pragma unroll
        for (int i = 0; i < 4; ++i) {
            int iss = wave * 4 + i;       // 0..15, each covers 8 rows (1 KiB)
            int row = 8 * iss + lrow;
            const _Float16* ga = A   + (size_t)(m0 + row) * K + k0 + lcol8;
            const _Float16* gh = Whi + (size_t)(n0 + row) * K + k0 + lcol8;
            const _Float16* gl = Wlo + (size_t)(n0 + row) * K + k0 + lcol8;
            __builtin_amdgcn_global_load_lds(
                (const __attribute__((address_space(1))) void*)ga,
                (__attribute__((address_space(3))) void*)(As + iss * 512), 16, 0, 0);
            __builtin_amdgcn_global_load_lds(
                (const __attribute__((address_space(1))) void*)gh,
                (__attribute__((address_space(3))) void*)(Bh + iss * 512), 16, 0, 0);
            __builtin_amdgcn_global_load_lds(
                (const __attribute__((address_space(1))) void*)gl,
                (__attribute__((address_space(3))) void*)(Bl + iss * 512), 16, 0, 0);
        }
        __syncthreads();
#pragma unroll
        for (int kk = 0; kk < 2; ++kk) {
            const int kb = kk * 32 + (lane >> 4) * 8;
            f16x8 af[4], bh[4], bl[4];
#pragma unroll
            for (int mi = 0; mi < 4; ++mi)
                af[mi] = *(const f16x8*)&As[(wr * 64 + mi * 16 + (lane & 15)) * 64 + kb];
#pragma unroll
            for (int ni = 0; ni < 4; ++ni) {
                int r = (wc * 64 + ni * 16 + (lane & 15)) * 64 + kb;
                bh[ni] = *(const f16x8*)&Bh[r];
                bl[ni] = *(const f16x8*)&Bl[r];
            }
#pragma unroll
            for (int mi = 0; mi < 4; ++mi)
#pragma unroll
                for (int ni = 0; ni < 4; ++ni) {
                    acc[mi][ni] = __builtin_amdgcn_mfma_f32_16x16x32_f16(
                        af[mi], bh[ni], acc[mi][ni], 0, 0, 0);
                    acc[mi][ni] = __builtin_amdgcn_mfma_f32_16x16x32_f16(
                        af[mi], bl[ni], acc[mi][ni], 0, 0, 0);
                }
        }
        __syncthreads();
    }

    const int crow0 = m0 + wr * 64 + (lane >> 4) * 4;
    const int ccol0 = n0 + wc * 64 + (lane & 15);
#pragma unroll
    for (int mi = 0; mi < 4; ++mi) {
#pragma unroll
        for (int ni = 0; ni < 4; ++ni) {
            int col = ccol0 + ni * 16;
            float bv = bias ? bias[col] : 0.f;
#pragma unroll
            for (int r = 0; r < 4; ++r) {
                int row = crow0 + mi * 16 + r;
                float v = acc[mi][ni][r] + bv;
                if (ACT == 1) v = relu_f(v);
                else if (ACT == 2) v = tanhf(v);
                C[(size_t)row * N + col] = (_Float16)v;
            }
        }
    }
}

// ---------------- fc1 MFMA GEMM (3-term split, fp32 out) ----------------------
__global__ __launch_bounds__(256) void gemm_fc1(
    const _Float16* __restrict__ Ahi, const _Float16* __restrict__ Alo,
    const _Float16* __restrict__ Whi, const _Float16* __restrict__ Wlo,
    const float* __restrict__ bias, float* __restrict__ C,
    int Mv, int N, int K)
{
    __shared__ _Float16 Ah[128 * 64];
    __shared__ _Float16 Al[128 * 64];
    __shared__ _Float16 Bh[128 * 64];
    __shared__ _Float16 Bl[128 * 64];
    const int tid = threadIdx.x;
    const int wave = tid >> 6, lane = tid & 63;
    const int m0 = blockIdx.y * 128, n0 = blockIdx.x * 128;
    const int wr = wave >> 1, wc = wave & 1;

    f32x4 acc[4][4];
#pragma unroll
    for (int i = 0; i < 4; ++i)
#pragma unroll
        for (int j = 0; j < 4; ++j) acc[i][j] = (f32x4){0.f, 0.f, 0.f, 0.f};

    const int lrow = lane >> 3;
    const int lcol8 = (lane & 7) * 8;

    for (int k0 = 0; k0 < K; k0 += 64) {
#pragma unroll
        for (int i = 0; i < 4; ++i) {
            int iss = wave * 4 + i;
            int row = 8 * iss + lrow;
            const _Float16* gah = Ahi + (size_t)(m0 + row) * K + k0 + lcol8;
            const _Float16* gal = Alo + (size_t)(m0 + row) * K + k0 + lcol8;
            const _Float16* gbh = Whi + (size_t)(n0 + row) * K + k0 + lcol8;
            const _Float16* gbl = Wlo + (size_t)(n0 + row) * K + k0 + lcol8;
            __builtin_amdgcn_global_load_lds(
                (const __attribute__((address_space(1))) void*)gah,
                (__attribute__((address_space(3))) void*)(Ah + iss * 512), 16, 0, 0);
            __builtin_amdgcn_global_load_lds(
                (const __attribute__((address_space(1))) void*)gal,
                (__attribute__((address_space(3))) void*)(Al + iss * 512), 16, 0, 0);
            __builtin_amdgcn_global_load_lds(
                (const __attribute__((address_space(1))) void*)gbh,
                (__attribute__((address_space(3))) void*)(Bh + iss * 512), 16, 0, 0);
            __builtin_amdgcn_global_load_lds(
                (const __attribute__((address_space(1))) void*)gbl,
                (__attribute__((address_space(3))) void*)(Bl + iss * 512), 16, 0, 0);
        }
        __syncthreads();
#pragma unroll
        for (int kk = 0; kk < 2; ++kk) {
            const int kb = kk * 32 + (lane >> 4) * 8;
            f16x8 ah[4], al[4], bh[4], bl[4];
#pragma unroll
            for (int mi = 0; mi < 4; ++mi) {
                int r = (wr * 64 + mi * 16 + (lane & 15)) * 64 + kb;
                ah[mi] = *(const f16x8*)&Ah[r];
                al[mi] = *(const f16x8*)&Al[r];
            }
#pragma unroll
            for (int ni = 0; ni < 4; ++ni) {
                int r = (wc * 64 + ni * 16 + (lane & 15)) * 64 + kb;
                bh[ni] = *(const f16x8*)&Bh[r];
                bl[ni] = *(const f16x8*)&Bl[r];
            }
#pragma unroll
            for (int mi = 0; mi < 4; ++mi)
#pragma unroll
                for (int ni = 0; ni < 4; ++ni) {
                    acc[mi][ni] = __builtin_amdgcn_mfma_f32_16x16x32_f16(
                        ah[mi], bh[ni], acc[mi][ni], 0, 0, 0);
                    acc[mi][ni] = __builtin_amdgcn_mfma_f32_16x16x32_f16(
                        ah[mi], bl[ni], acc[mi][ni], 0, 0, 0);
                    acc[mi][ni] = __builtin_amdgcn_mfma_f32_16x16x32_f16(
                        al[mi], bh[ni], acc[mi][ni], 0, 0, 0);
                }
        }
        __syncthreads();
    }

    const int crow0 = m0 + wr * 64 + (lane >> 4) * 4;
    const int ccol0 = n0 + wc * 64 + (lane & 15);
#pragma unroll
    for (int mi = 0; mi < 4; ++mi) {
#pragma unroll
        for (int ni = 0; ni < 4; ++ni) {
            int col = ccol0 + ni * 16;
            float bv = bias[col];
#pragma unroll
            for (int r = 0; r < 4; ++r) {
                int row = crow0 + mi * 16 + r;
                if (row < Mv)
                    C[(size_t)row * N + col] = acc[mi][ni][r] + bv;
            }
        }
    }
}

// ---------------- counting sort of edges by dst ----------------
__global__ void count_k(const int* __restrict__ dst, int* __restrict__ cnt, int E)
{
    int e = blockIdx.x * blockDim.x + threadIdx.x;
    if (e < E) atomicAdd(&cnt[dst[e]], 1);
}

// 3-phase exclusive scan of cnt[n]
__global__ __launch_bounds__(256) void scan1_k(
    const int* __restrict__ cnt, int* __restrict__ offs,
    int* __restrict__ bsum, int n)
{
    __shared__ int sh[256];
    int t = threadIdx.x, idx = blockIdx.x * 256 + t;
    int v = (idx < n) ? cnt[idx] : 0;
    sh[t] = v;
    __syncthreads();
    for (int o = 1; o < 256; o <<= 1) {
        int a = (t >= o) ? sh[t - o] : 0;
        __syncthreads();
        sh[t] += a;
        __syncthreads();
    }
    if (idx < n) offs[idx] = sh[t] - v;
    if (t == 255) bsum[blockIdx.x] = sh[255];
}

__global__ __launch_bounds__(256) void scan2_k(int* __restrict__ bsum, int nb)
{
    __shared__ int sh[256];
    int t = threadIdx.x;
    int v = (t < nb) ? bsum[t] : 0;
    sh[t] = v;
    __syncthreads();
    for (int o = 1; o < 256; o <<= 1) {
        int a = (t >= o) ? sh[t - o] : 0;
        __syncthreads();
        sh[t] += a;
        __syncthreads();
    }
    if (t < nb) bsum[t] = sh[t] - v;
}

__global__ __launch_bounds__(256) void scan3_k(
    int* __restrict__ offs, const int* __restrict__ bsum,
    int* __restrict__ cursor, int n, int E)
{
    int idx = blockIdx.x * 256 + threadIdx.x;
    if (idx < n) {
        int o = offs[idx] + bsum[blockIdx.x];
        offs[idx] = o;
        cursor[idx] = o;
    }
    if (idx == 0) offs[n] = E;
}

// scatter: one fused 8B record per edge (src, ea-bits) -> single random store
__global__ void scatter_k(const int* __restrict__ dst, const int* __restrict__ src,
                          const float* __restrict__ ea, int* __restrict__ cursor,
                          int2* __restrict__ esrc, int E)
{
    int e = blockIdx.x * blockDim.x + threadIdx.x;
    if (e < E) {
        int p = atomicAdd(&cursor[dst[e]], 1);
        esrc[p] = make_int2(src[e], __float_as_int(ea[e]));
    }
}

// start[g] = lower_bound(batch, g)
__global__ void start_k(const int* __restrict__ batch, int* __restrict__ start,
                        int n, int B)
{
    int g = blockIdx.x * blockDim.x + threadIdx.x;
    if (g > B) return;
    int lo = 0, hi = n;
    while (lo < hi) {
        int mid = (lo + hi) >> 1;
        if (batch[mid] < g) lo = mid + 1; else hi = mid;
    }
    start[g] = lo;
}

// ---------------- edge aggregation: one wave per dst, 2 edges/iter ------------
// lane L: half = L>>5 handles edge (pair base + half); features (L&31)*8..+7.
// out[d] = relu(xw[d]) + sum_e relu(xw[src_e] + ea_e*we)   (lb folded into xw)
__global__ __launch_bounds__(256) void aggregate_k(
    const _Float16* __restrict__ xw, const float* __restrict__ we,
    const int2* __restrict__ esrc, const int* __restrict__ offs,
    _Float16* __restrict__ out, int n)
{
    int w = (blockIdx.x * blockDim.x + threadIdx.x) >> 6;
    if (w >= n) return;
    const int lane = threadIdx.x & 63;
    const int half = lane >> 5;
    const int f8 = (lane & 31) << 3;     // feature base (8 per lane)

    float we8[8];
    *(float4*)&we8[0] = *(const float4*)(we + f8);
    *(float4*)&we8[4] = *(const float4*)(we + f8 + 4);

    // self term (half 0 only; halves hold duplicate feature slices)
    f16x8 xs = *(const f16x8*)(xw + (size_t)w * HIDF + f8);
    float acc[8];
#pragma unroll
    for (int j = 0; j < 8; ++j)
        acc[j] = (half == 0) ? relu_f((float)xs[j]) : 0.f;

    const int e0 = offs[w], e1 = offs[w + 1];
    const int cntE = e1 - e0;
    const int fullPairs = cntE >> 1;

    int t = 0;
    for (; t + 4 <= fullPairs; t += 4) {   // 4 pairs = 8 edges, all valid
        int2 p[4]; f16x8 v[4];
#pragma unroll
        for (int q = 0; q < 4; ++q) p[q] = esrc[e0 + 2 * (t + q) + half];
#pragma unroll
        for (int q = 0; q < 4; ++q)
            v[q] = *(const f16x8*)(xw + (size_t)p[q].x * HIDF + f8);
#pragma unroll
        for (int q = 0; q < 4; ++q) {
            float a = __int_as_float(p[q].y);
#pragma unroll
            for (int j = 0; j < 8; ++j)
                acc[j] += relu_f(fmaf(a, we8[j], (float)v[q][j]));
        }
    }
    for (; t < fullPairs; ++t) {
        int2 p = esrc[e0 + 2 * t + half];
        f16x8 v = *(const f16x8*)(xw + (size_t)p.x * HIDF + f8);
        float a = __int_as_float(p.y);
#pragma unroll
        for (int j = 0; j < 8; ++j)
            acc[j] += relu_f(fmaf(a, we8[j], (float)v[j]));
    }
    if ((cntE & 1) && half == 0) {        // last odd edge, half 0 only
        int2 p = esrc[e1 - 1];
        f16x8 v = *(const f16x8*)(xw + (size_t)p.x * HIDF + f8);
        float a = __int_as_float(p.y);
#pragma unroll
        for (int j = 0; j < 8; ++j)
            acc[j] += relu_f(fmaf(a, we8[j], (float)v[j]));
    }

    // merge halves
#pragma unroll
    for (int j = 0; j < 8; ++j)
        acc[j] += __shfl_xor(acc[j], 32);

    if (half == 0) {
        f16x8 o;
#pragma unroll
        for (int j = 0; j < 8; ++j) o[j] = (_Float16)acc[j];
        *(f16x8*)(out + (size_t)w * HIDF + f8) = o;
    }
}

// ---------------- gate: gate[i] = sigmoid(dot(t[i], g2w) + g2b) ---------------
__global__ __launch_bounds__(256) void gate_k(
    const _Float16* __restrict__ t, const float* __restrict__ g2w,
    const float* __restrict__ g2b, float* __restrict__ gate, int n)
{
    int w = (blockIdx.x * blockDim.x + threadIdx.x) >> 6;
    if (w >= n) return;
    int lane = threadIdx.x & 63;
    f16x4 tv = *(const f16x4*)(t + (size_t)w * HIDF + (lane << 2));
    float4 g = *(const float4*)(g2w + (lane << 2));
    float s = (float)tv[0] * g.x + (float)tv[1] * g.y
            + (float)tv[2] * g.z + (float)tv[3] * g.w;
    for (int o = 32; o; o >>= 1) s += __shfl_xor(s, o);
    if (lane == 0) gate[w] = 1.f / (1.f + expf(-(s + g2b[0])));
}

// ---------------- pooling ----------------
__global__ __launch_bounds__(256) void pool_k(
    const _Float16* __restrict__ x, const float* __restrict__ gate,
    const int* __restrict__ start, float* __restrict__ pooled, int B)
{
    int w = (blockIdx.x * blockDim.x + threadIdx.x) >> 6;
    if (w >= B) return;
    int lane = threadIdx.x & 63;
    int f = lane << 2;
    float4 acc = make_float4(0.f, 0.f, 0.f, 0.f);
    int i0 = start[w], i1 = start[w + 1];
    for (int i = i0; i < i1; ++i) {
        float gi = gate[i];
        f16x4 v = *(const f16x4*)(x + (size_t)i * HIDF + f);
        acc.x = fmaf(gi, (float)v[0], acc.x);
        acc.y = fmaf(gi, (float)v[1], acc.y);
        acc.z = fmaf(gi, (float)v[2], acc.z);
        acc.w = fmaf(gi, (float)v[3], acc.w);
    }
    *(float4*)(pooled + (size_t)w * HIDF + f) = acc;
}

// ---------------- BN stats per column ----------------
__global__ __launch_bounds__(256) void bnstats_k(
    const float* __restrict__ h, float* __restrict__ mu,
    float* __restrict__ rs, int B)
{
    int j = blockIdx.x;
    int tid = threadIdx.x;
    float s = 0.f, s2 = 0.f;
    for (int g = tid; g < B; g += 256) {
        float v = h[(size_t)g * HIDF + j];
        s += v;
        s2 = fmaf(v, v, s2);
    }
    __shared__ float sh[256], sh2[256];
    sh[tid] = s; sh2[tid] = s2;
    __syncthreads();
    for (int o = 128; o; o >>= 1) {
        if (tid < o) { sh[tid] += sh[tid + o]; sh2[tid] += sh2[tid + o]; }
        __syncthreads();
    }
    if (tid == 0) {
        float m = sh[0] / (float)B;
        float var = sh2[0] / (float)B - m * m;
        if (var < 0.f) var = 0.f;
        mu[j] = m;
        rs[j] = rsqrtf(var + 1e-5f);
    }
}

// ---------------- final ----------------
__global__ __launch_bounds__(256) void final_k(
    const float* __restrict__ h, const float* __restrict__ mu,
    const float* __restrict__ rs, const float* __restrict__ gamma,
    const float* __restrict__ beta, const float* __restrict__ w2,
    const float* __restrict__ b2, float* __restrict__ out, int B)
{
    int g = blockIdx.x;
    int j = threadIdx.x;
    float v = h[(size_t)g * HIDF + j];
    v = (v - mu[j]) * rs[j] * gamma[j] + beta[j];
    v = relu_f(v);
    float term = v * w2[j];
    __shared__ float sh[256];
    sh[j] = term;
    __syncthreads();
    for (int o = 128; o; o >>= 1) {
        if (j < o) sh[j] += sh[j + o];
        __syncthreads();
    }
    if (j == 0) out[g] = sh[0] + b2[0];
}

extern "C" void kernel_launch(void* const* d_in, const int* in_sizes, int n_in,
                              void* d_out, int out_size, void* d_ws, size_t ws_size,
                              hipStream_t stream)
{
    const float* x      = (const float*)d_in[0];
    const int*   ei     = (const int*)d_in[1];
    const float* ea     = (const float*)d_in[2];
    const float* fp     = (const float*)d_in[3];
    const int*   batch  = (const int*)d_in[4];
    const float* lin_w  = (const float*)d_in[5];
    const float* lin_b  = (const float*)d_in[6];
    const float* upd_w  = (const float*)d_in[7];
    const float* upd_b  = (const float*)d_in[8];
    const float* g1w    = (const float*)d_in[9];
    const float* g1b    = (const float*)d_in[10];
    const float* g2w    = (const float*)d_in[11];
    const float* g2b    = (const float*)d_in[12];
    const float* fc1w   = (const float*)d_in[13];
    const float* fc1b   = (const float*)d_in[14];
    const float* gamma  = (const float*)d_in[15];
    const float* beta   = (const float*)d_in[16];
    const float* fc2w   = (const float*)d_in[17];
    const float* fc2b   = (const float*)d_in[18];
    float* out = (float*)d_out;

    const int n = in_sizes[0] / HIDF;        // 50000
    const int E = in_sizes[1] / 2;           // 800000
    const int B = in_sizes[3] / FPDIM;       // 2000
    const int L = in_sizes[5] / (257 * 256); // 4
    const int* srcArr = ei;
    const int* dstArr = ei + E;
    const int nb = (n + 255) / 256;

    // ---- workspace layout ----
    char* w = (char*)d_ws;
    _Float16* xh   = (_Float16*)w;  w += (size_t)MPAD * HIDF * 2;   // node state
    _Float16* bufA = (_Float16*)w;  w += (size_t)MPAD * HIDF * 2;   // xw / tanh-out
    _Float16* bufB = (_Float16*)w;  w += (size_t)MPAD * HIDF * 2;   // aggr out
    _Float16* whi = (_Float16*)w;  w += (size_t)9 * 65536 * 2;
    _Float16* wlo = (_Float16*)w;  w += (size_t)9 * 65536 * 2;
    _Float16* fahi = (_Float16*)w; w += (size_t)FCM * FCK * 2;
    _Float16* falo = (_Float16*)w; w += (size_t)FCM * FCK * 2;
    _Float16* fwhi = (_Float16*)w; w += (size_t)HIDF * FCK * 2;
    _Float16* fwlo = (_Float16*)w; w += (size_t)HIDF * FCK * 2;
    int2*  esrc   = (int2*)w;   w += (size_t)E * 8;
    int*   offs   = (int*)w;    w += ((size_t)n + 4) * 4;
    int*   cursor = (int*)w;    w += ((size_t)n + 4) * 4;
    int*   cnt    = (int*)w;    w += (size_t)n * 4;
    int*   bsum   = (int*)w;    w += 256 * 4;
    int*   startA = (int*)w;    w += ((size_t)B + 4) * 4;
    float* gateA  = (float*)w;  w += (size_t)n * 4;
    float* pooled = (float*)w;  w += (size_t)B * HIDF * 4;
    float* h      = (float*)w;  w += (size_t)B * HIDF * 4;
    float* mu     = (float*)w;  w += 256 * 4;
    float* rs     = (float*)w;  w += 256 * 4;

    // ---- CSR build (counting sort by dst) + batch starts ----
    hipMemsetAsync(cnt, 0, (size_t)n * 4, stream);
    count_k<<<(E + 255) / 256, 256, 0, stream>>>(dstArr, cnt, E);
    scan1_k<<<nb, 256, 0, stream>>>(cnt, offs, bsum, n);
    scan2_k<<<1, 256, 0, stream>>>(bsum, nb);
    scan3_k<<<nb, 256, 0, stream>>>(offs, bsum, cursor, n, E);
    scatter_k<<<(E + 255) / 256, 256, 0, stream>>>(dstArr, srcArr, ea, cursor, esrc, E);
    start_k<<<(B + 256) / 256, 256, 0, stream>>>(batch, startA, n, B);

    // ---- input fp16 conversion + weight split ----
    convxh_k<<<(MPAD * 64 + 255) / 256, 256, 0, stream>>>(x, xh, n);
    for (int l = 0; l < L; ++l) {
        convw_k<<<256, 256, 0, stream>>>(lin_w + (size_t)l * 257 * 256,
                                         whi + (size_t)l * 65536, wlo + (size_t)l * 65536);
        convw_k<<<256, 256, 0, stream>>>(upd_w + (size_t)l * 65536,
                                         whi + (size_t)(4 + l) * 65536, wlo + (size_t)(4 + l) * 65536);
    }
    convw_k<<<256, 256, 0, stream>>>(g1w, whi + (size_t)8 * 65536, wlo + (size_t)8 * 65536);
    convfc1w_k<<<(HIDF * FCK + 255) / 256, 256, 0, stream>>>(fc1w, fwhi, fwlo);

    // ---- message passing: xh -> gemm1(+lb) -> bufA -> aggregate -> bufB -> gemm2 -> xh
    dim3 ggm(HIDF / 128, MPAD / 128);
    for (int l = 0; l < L; ++l) {
        const float* we = lin_w + (size_t)l * 257 * 256 + 256 * 256;  // edge row (1x256)
        const float* lb = lin_b + (size_t)l * 256;
        gemm_f16<0><<<ggm, 256, 0, stream>>>(xh, whi + (size_t)l * 65536,
                                             wlo + (size_t)l * 65536, lb,
                                             bufA, MPAD, HIDF, HIDF);
        aggregate_k<<<(n * 64 + 255) / 256, 256, 0, stream>>>(
            bufA, we, esrc, offs, bufB, n);
        gemm_f16<1><<<ggm, 256, 0, stream>>>(bufB, whi + (size_t)(4 + l) * 65536,
                                             wlo + (size_t)(4 + l) * 65536,
                                             upd_b + (size_t)l * 256, xh, MPAD, HIDF, HIDF);
    }

    // ---- gating + pooling ----
    gemm_f16<2><<<ggm, 256, 0, stream>>>(xh, whi + (size_t)8 * 65536,
                                         wlo + (size_t)8 * 65536, g1b,
                                         bufA, MPAD, HIDF, HIDF);
    gate_k<<<(n * 64 + 255) / 256, 256, 0, stream>>>(bufA, g2w, g2b, gateA, n);
    pool_k<<<(B * 64 + 255) / 256, 256, 0, stream>>>(xh, gateA, startA, pooled, B);

    // ---- head: fc1 via 3-term split MFMA, then BN + final (fp32) ----
    convfc1a_k<<<(FCM * FCK + 255) / 256, 256, 0, stream>>>(pooled, fp, fahi, falo, B);
    dim3 ggf(HIDF / 128, FCM / 128);
    gemm_fc1<<<ggf, 256, 0, stream>>>(fahi, falo, fwhi, fwlo, fc1b, h, B, HIDF, FCK);
    bnstats_k<<<256, 256, 0, stream>>>(h, mu, rs, B);
    final_k<<<B, 256, 0, stream>>>(h, mu, rs, gamma, beta, fc2w, fc2b, out, B);
}